// Round 15
// baseline (4517.730 us; speedup 1.0000x reference)
//
#include <hip/hip_runtime.h>
#include <math.h>

namespace {

constexpr int Bq = 64, Pq = 196, Dq = 2048, Eq = 512, Vq = 10000, Tq = 32, T1q = 33;
constexpr size_t N_IMG = (size_t)Bq * Pq * Dq;  // 25,690,112
constexpr int NBLK = 256;

typedef __attribute__((ext_vector_type(8))) short bf16x8;
typedef __attribute__((ext_vector_type(4))) float f32x4;

__device__ __forceinline__ float sigf(float x) { return 1.f / (1.f + expf(-x)); }

__device__ __forceinline__ ushort f2bf(float f) {
  union { float f; unsigned u; } v; v.f = f;
  unsigned u = v.u;
  return (ushort)((u + 0x7fffu + ((u >> 16) & 1u)) >> 16);  // RNE
}
__device__ __forceinline__ float bf2f(ushort h) {
  union { unsigned u; float f; } v; v.u = ((unsigned)h) << 16;
  return v.f;
}

// ---- grid barrier (R10-proven) ----
__device__ __forceinline__ void gsync(unsigned* bar) {
  __syncthreads();
  if (threadIdx.x == 0) {
    __builtin_amdgcn_fence(__ATOMIC_RELEASE, "agent");
    unsigned g = __hip_atomic_load(&bar[144], __ATOMIC_RELAXED, __HIP_MEMORY_SCOPE_AGENT);
    unsigned shard = ((unsigned)blockIdx.x & 7u) * 16u;
    unsigned a = __hip_atomic_fetch_add(&bar[shard], 1u, __ATOMIC_RELAXED,
                                        __HIP_MEMORY_SCOPE_AGENT);
    if (a == 31u) {
      unsigned tot = __hip_atomic_fetch_add(&bar[128], 32u, __ATOMIC_RELAXED,
                                            __HIP_MEMORY_SCOPE_AGENT);
      if (tot == (unsigned)NBLK - 32u) {
        for (unsigned i = 0; i < 8; ++i)
          __hip_atomic_store(&bar[i * 16u], 0u, __ATOMIC_RELAXED, __HIP_MEMORY_SCOPE_AGENT);
        __hip_atomic_store(&bar[128], 0u, __ATOMIC_RELAXED, __HIP_MEMORY_SCOPE_AGENT);
        __hip_atomic_store(&bar[144], g + 1u, __ATOMIC_RELEASE, __HIP_MEMORY_SCOPE_AGENT);
      }
    }
    while (__hip_atomic_load(&bar[144], __ATOMIC_RELAXED, __HIP_MEMORY_SCOPE_AGENT) == g) {
      __builtin_amdgcn_s_sleep(1);
    }
    __builtin_amdgcn_fence(__ATOMIC_ACQUIRE, "agent");
  }
  __syncthreads();
}

__global__ void bar_init(unsigned* bar) { bar[threadIdx.x] = 0u; }

// ---------------- prolog kernels (unchanged) ----------------

__global__ __launch_bounds__(256) void cvt_all(const float* __restrict__ img,
                                               const float* __restrict__ Watt,
                                               ushort* __restrict__ img16,
                                               ushort* __restrict__ Watt16) {
  int u = blockIdx.x * 256 + threadIdx.x;
  constexpr int NU_IMG = (int)(N_IMG / 8);
  const float* src; ushort* dst; int off;
  if (u < NU_IMG) { src = img; dst = img16; off = u; }
  else { src = Watt; dst = Watt16; off = u - NU_IMG; }
  const float4 a = reinterpret_cast<const float4*>(src)[2 * (size_t)off];
  const float4 b = reinterpret_cast<const float4*>(src)[2 * (size_t)off + 1];
  union { ushort s[8]; uint4 v; } o;
  o.s[0] = f2bf(a.x); o.s[1] = f2bf(a.y); o.s[2] = f2bf(a.z); o.s[3] = f2bf(a.w);
  o.s[4] = f2bf(b.x); o.s[5] = f2bf(b.y); o.s[6] = f2bf(b.z); o.s[7] = f2bf(b.w);
  reinterpret_cast<uint4*>(dst)[off] = o.v;
}

__global__ __launch_bounds__(256) void avg_kernel(const float* __restrict__ img,
                                                  float* __restrict__ avg) {
  int idx = blockIdx.x * 256 + threadIdx.x;
  int b = idx >> 11, d = idx & (Dq - 1);
  const float* ib = img + (size_t)b * Pq * Dq + d;
  float s = 0.f;
  for (int p = 0; p < Pq; ++p) s += ib[(size_t)p * Dq];
  avg[idx] = s * (1.f / Pq);
}

__global__ __launch_bounds__(256) void init_partial(const float* __restrict__ avg,
                                                    const float* __restrict__ Wh,
                                                    const float* __restrict__ Wc,
                                                    float* __restrict__ P) {
  __shared__ float smem[4224];
  float (*As)[66] = reinterpret_cast<float(*)[66]>(smem);
  float (*Ws)[66] = reinterpret_cast<float(*)[66]>(smem + 32 * 66);
  const float* W = blockIdx.z ? Wc : Wh;
  float* Pout = P + (size_t)blockIdx.z * 8 * Bq * Eq + (size_t)blockIdx.y * Bq * Eq;
  const int tid = threadIdx.x;
  const int tx = tid & 15, ty = tid >> 4;
  const int n0 = blockIdx.x * 64, kbeg = blockIdx.y * 256;
  float acc[4][4] = {};
  for (int it = 0; it < 8; ++it) {
    const int k0 = kbeg + it * 32;
#pragma unroll
    for (int i = 0; i < 2; ++i) {
      int idx = tid + i * 256, r = idx >> 3, c = (idx & 7) << 2;
      const float4 a = *reinterpret_cast<const float4*>(avg + (size_t)r * Dq + k0 + c);
      As[c + 0][r] = a.x; As[c + 1][r] = a.y; As[c + 2][r] = a.z; As[c + 3][r] = a.w;
      const float4 w = *reinterpret_cast<const float4*>(W + (size_t)(n0 + r) * Dq + k0 + c);
      Ws[c + 0][r] = w.x; Ws[c + 1][r] = w.y; Ws[c + 2][r] = w.z; Ws[c + 3][r] = w.w;
    }
    __syncthreads();
#pragma unroll
    for (int k = 0; k < 32; ++k) {
      float av[4], wv[4];
#pragma unroll
      for (int i2 = 0; i2 < 4; ++i2) { av[i2] = As[k][ty * 4 + i2]; wv[i2] = Ws[k][tx * 4 + i2]; }
#pragma unroll
      for (int mi = 0; mi < 4; ++mi)
#pragma unroll
        for (int ni = 0; ni < 4; ++ni) acc[mi][ni] = fmaf(av[mi], wv[ni], acc[mi][ni]);
    }
    __syncthreads();
  }
#pragma unroll
  for (int ni = 0; ni < 4; ++ni)
#pragma unroll
    for (int mi = 0; mi < 4; ++mi)
      Pout[(size_t)(ty * 4 + mi) * Eq + n0 + tx * 4 + ni] = acc[mi][ni];
}

__global__ __launch_bounds__(256) void init_epi(const float* __restrict__ P,
                                                const float* __restrict__ b_h,
                                                const float* __restrict__ b_c,
                                                float* __restrict__ h0,
                                                float* __restrict__ c) {
  int idx = blockIdx.x * 256 + threadIdx.x;
  int which = idx >> 15, j = idx & 32767;
  int b = j >> 9, e = j & 511;
  const float* Pp = P + (size_t)which * 8 * Bq * Eq;
  float s = which ? b_c[e] : b_h[e];
#pragma unroll
  for (int sp = 0; sp < 8; ++sp) s += Pp[((size_t)sp * Bq + b) * Eq + e];
  float v = tanhf(s);
  if (which) c[j] = v; else h0[j] = v;
}

// fproj16 = bf16(img16 @ Watt16^T + b_Watt) via bf16 MFMA. grid (98, 8).
__global__ __launch_bounds__(256) void fproj_mfma(const ushort* __restrict__ A16,
                                                  const ushort* __restrict__ B16,
                                                  const float* __restrict__ bias,
                                                  ushort* __restrict__ C16) {
  __shared__ ushort As[128 * 32];
  __shared__ ushort Bs[64 * 32];
  const int tid = threadIdx.x;
  const int lane = tid & 63, wave = tid >> 6;
  const int m0 = blockIdx.x * 128, n0 = blockIdx.y * 64;
  const int wr = (wave >> 1) * 64, wc = (wave & 1) * 32;
  f32x4 acc[4][2] = {};
  const int ar = tid >> 1, seg = (tid & 1) * 16;
  const int br = (tid & 127) >> 1;
  for (int k0 = 0; k0 < Dq; k0 += 32) {
    const ushort* ga = A16 + (size_t)(m0 + ar) * Dq + k0 + seg;
    uint4 a0 = *reinterpret_cast<const uint4*>(ga);
    uint4 a1 = *reinterpret_cast<const uint4*>(ga + 8);
    unsigned ab = (unsigned)(ar * 64 + seg * 2);
    unsigned sw = (unsigned)((ar & 7) << 4);
    *reinterpret_cast<uint4*>(reinterpret_cast<char*>(As) + (ab ^ sw)) = a0;
    *reinterpret_cast<uint4*>(reinterpret_cast<char*>(As) + ((ab + 16) ^ sw)) = a1;
    if (tid < 128) {
      const ushort* gb = B16 + (size_t)(n0 + br) * Dq + k0 + seg;
      uint4 b0 = *reinterpret_cast<const uint4*>(gb);
      uint4 b1 = *reinterpret_cast<const uint4*>(gb + 8);
      unsigned bb = (unsigned)(br * 64 + seg * 2);
      unsigned sb = (unsigned)((br & 7) << 4);
      *reinterpret_cast<uint4*>(reinterpret_cast<char*>(Bs) + (bb ^ sb)) = b0;
      *reinterpret_cast<uint4*>(reinterpret_cast<char*>(Bs) + ((bb + 16) ^ sb)) = b1;
    }
    __syncthreads();
    const int g = lane >> 4;
    bf16x8 af[4], bfr[2];
#pragma unroll
    for (int i = 0; i < 4; ++i) {
      int row = wr + i * 16 + (lane & 15);
      af[i] = *reinterpret_cast<const bf16x8*>(
          reinterpret_cast<char*>(As) + ((unsigned)(row * 64 + g * 16) ^ ((row & 7) << 4)));
    }
#pragma unroll
    for (int j = 0; j < 2; ++j) {
      int col = wc + j * 16 + (lane & 15);
      bfr[j] = *reinterpret_cast<const bf16x8*>(
          reinterpret_cast<char*>(Bs) + ((unsigned)(col * 64 + g * 16) ^ ((col & 7) << 4)));
    }
#pragma unroll
    for (int i = 0; i < 4; ++i)
#pragma unroll
      for (int j = 0; j < 2; ++j)
        acc[i][j] = __builtin_amdgcn_mfma_f32_16x16x32_bf16(af[i], bfr[j], acc[i][j], 0, 0, 0);
    __syncthreads();
  }
#pragma unroll
  for (int i = 0; i < 4; ++i) {
#pragma unroll
    for (int j = 0; j < 2; ++j) {
      int n = n0 + wc + j * 16 + (lane & 15);
      float bv = bias[n];
#pragma unroll
      for (int q = 0; q < 4; ++q) {
        int m = m0 + wr + i * 16 + (lane >> 4) * 4 + q;
        C16[(size_t)m * Eq + n] = f2bf(acc[i][j][q] + bv);
      }
    }
  }
}

// ---------------- persistent step-loop ----------------

struct StepParams {
  const int* caps;
  const float* emb;
  const float* U_att;
  const float* b_Uatt;
  const float* W_fbeta;
  const float* b_fbeta;
  const float* v_att;
  const float* b_vatt;
  const float* W_ih;
  const float* b_ih;
  const float* W_hh;
  const float* b_hh;
  const ushort* img16;
  const ushort* fproj16;
  const float* h0;
  float* c;
  float* hseq;
  float* ctxg;
  float* ev_g;
  float* Pah;
  float* Pfb;
  float* Pwh;
  float* Pge;
  float* Pg;
  float* alphas_out;
  unsigned* bar;
};

// 64x64 out tile over a K=256 slice; W in LDS bf16; 1024 threads, acc[4].
template <int MODE>
__device__ __forceinline__ void gemm_ldsw(
    const float* __restrict__ A, int lda, int kbase,
    const ushort (* __restrict__ Ws)[64],
    const float* __restrict__ emb, const int* __restrict__ caps, int t,
    float (*As)[66], int tid, float acc[4]) {
  const int tx = tid & 15, ty = tid >> 4;
  const int cc = (tid & 15) * 2;
  float2 pa;
  auto loadA = [&](int kc) {
    if (MODE == 1) {
      int tok = caps[ty * T1q + t];
      pa = *reinterpret_cast<const float2*>(emb + (size_t)tok * Eq + kbase + kc * 32 + cc);
    } else {
      pa = *reinterpret_cast<const float2*>(A + (size_t)ty * lda + kbase + kc * 32 + cc);
    }
  };
  loadA(0);
  for (int kc = 0; kc < 8; ++kc) {
    As[cc + 0][ty] = pa.x; As[cc + 1][ty] = pa.y;
    __syncthreads();
    if (kc < 7) loadA(kc + 1);
#pragma unroll
    for (int k = 0; k < 32; ++k) {
      float av = As[k][ty];
      uint2 wu = *reinterpret_cast<const uint2*>(&Ws[kc * 32 + k][tx * 4]);
      acc[0] = fmaf(av, bf2f((ushort)(wu.x & 0xffffu)), acc[0]);
      acc[1] = fmaf(av, bf2f((ushort)(wu.x >> 16)), acc[1]);
      acc[2] = fmaf(av, bf2f((ushort)(wu.y & 0xffffu)), acc[2]);
      acc[3] = fmaf(av, bf2f((ushort)(wu.y >> 16)), acc[3]);
    }
    __syncthreads();
  }
}

__global__ __launch_bounds__(1024) void step_loop(StepParams p) {
  __shared__ ushort WsRole[256][64];  // 32 KB
  __shared__ ushort WsCtx[256][64];   // 32 KB
  __shared__ float As[32][66];        // 8.25 KB
  __shared__ float scr[4608];         // 18 KB: pc[4096] | al[196@4096] | red[256@4352]
  const int blk = blockIdx.x;
  const int tid = threadIdx.x;

  // ---- stage weights to LDS once (bf16) ----
  {
    const float* Wsrc = nullptr; int n0 = 0, koff = 0, ld = Eq;
    if (blk < 16)       { Wsrc = p.U_att;   n0 = (blk & 7) * 64;  koff = (blk >> 3) * 256; }
    else if (blk < 80)  { int i2 = blk - 16;  Wsrc = p.W_fbeta; n0 = (i2 & 31) * 64; koff = (i2 >> 5) * 256; }
    else if (blk < 144) { int i2 = blk - 80;  Wsrc = p.W_hh;    n0 = (i2 & 31) * 64; koff = (i2 >> 5) * 256; }
    else if (blk < 208) { int i2 = blk - 144; Wsrc = p.W_ih;    n0 = (i2 & 31) * 64; koff = (i2 >> 5) * 256; ld = Eq + Dq; }
    if (Wsrc) {
      for (int i = tid; i < 4096; i += 1024) {
        int r = i >> 6, c4 = (i & 63) << 2;
        const float4 w = *reinterpret_cast<const float4*>(Wsrc + (size_t)(n0 + r) * ld + koff + c4);
        WsRole[c4 + 0][r] = f2bf(w.x); WsRole[c4 + 1][r] = f2bf(w.y);
        WsRole[c4 + 2][r] = f2bf(w.z); WsRole[c4 + 3][r] = f2bf(w.w);
      }
    }
    int n0c = (blk & 31) * 64, kc = (blk >> 5) * 256;
    for (int i = tid; i < 4096; i += 1024) {
      int r = i >> 6, c4 = (i & 63) << 2;
      const float4 w = *reinterpret_cast<const float4*>(
          p.W_ih + (size_t)(n0c + r) * (Eq + Dq) + Eq + kc + c4);
      WsCtx[c4 + 0][r] = f2bf(w.x); WsCtx[c4 + 1][r] = f2bf(w.y);
      WsCtx[c4 + 2][r] = f2bf(w.z); WsCtx[c4 + 3][r] = f2bf(w.w);
    }
    __syncthreads();
  }

  const int tx = tid & 15, ty = tid >> 4;
  const int n0c = (blk & 31) * 64, ksc = blk >> 5;

  for (int t = 0; t < Tq; ++t) {
    const float* hc = (t == 0) ? p.h0 : p.hseq + (size_t)(t - 1) * Bq * Eq;

    // ---- PA: att_h | fbeta | Whh | emb-gates (LDS-W GEMM partials) ----
    if (blk < 208) {
      float acc[4] = {};
      float* Pout; int n0, Npad;
      if (blk < 16) {
        int ks = blk >> 3; n0 = (blk & 7) * 64; Npad = Eq;
        gemm_ldsw<0>(hc, Eq, ks * 256, WsRole, nullptr, nullptr, t, As, tid, acc);
        Pout = p.Pah + (size_t)ks * Bq * Eq;
      } else if (blk < 80) {
        int i2 = blk - 16, ks = i2 >> 5; n0 = (i2 & 31) * 64; Npad = Dq;
        gemm_ldsw<0>(hc, Eq, ks * 256, WsRole, nullptr, nullptr, t, As, tid, acc);
        Pout = p.Pfb + (size_t)ks * Bq * Dq;
      } else if (blk < 144) {
        int i2 = blk - 80, ks = i2 >> 5; n0 = (i2 & 31) * 64; Npad = Dq;
        gemm_ldsw<0>(hc, Eq, ks * 256, WsRole, nullptr, nullptr, t, As, tid, acc);
        Pout = p.Pwh + (size_t)ks * Bq * Dq;
      } else {
        int i2 = blk - 144, ks = i2 >> 5; n0 = (i2 & 31) * 64; Npad = Dq;
        gemm_ldsw<1>(nullptr, 0, ks * 256, WsRole, p.emb, p.caps, t, As, tid, acc);
        Pout = p.Pge + (size_t)ks * Bq * Dq;
      }
#pragma unroll
      for (int ni = 0; ni < 4; ++ni)
        Pout[(size_t)ty * Npad + n0 + tx * 4 + ni] = acc[ni];
    }
    gsync(p.bar);

    // ---- PB1: e-scores, p-split 4 blocks/b, uint4 loads, 2 p's in flight ----
    {
      const int b = blk >> 2, pq = blk & 3;
      const int lane = tid & 63, wv = tid >> 6;
      float* ah = scr; float* vs = scr + 512;
      if (tid < Eq) {
        ah[tid] = p.b_Uatt[tid] + p.Pah[(size_t)b * Eq + tid]
                + p.Pah[(size_t)Bq * Eq + b * Eq + tid];
        vs[tid] = p.v_att[tid];
      }
      __syncthreads();
      const float bv = p.b_vatt[0];
      const int pbeg = pq * 49, pend = pbeg + 49;
      const int k8 = lane * 8;
#pragma unroll
      for (int it = 0; it < 2; ++it) {
        int pA = pbeg + wv + it * 32, pB = pA + 16;
        bool vA = pA < pend, vB = pB < pend;
        uint4 va, vb2;
        if (vA) va = *reinterpret_cast<const uint4*>(p.fproj16 + ((size_t)b * Pq + pA) * Eq + k8);
        if (vB) vb2 = *reinterpret_cast<const uint4*>(p.fproj16 + ((size_t)b * Pq + pB) * Eq + k8);
        float sA = 0.f, sB = 0.f;
        if (vA) {
          const unsigned u[4] = {va.x, va.y, va.z, va.w};
#pragma unroll
          for (int j = 0; j < 4; ++j) {
            sA = fmaf(tanhf(bf2f((ushort)(u[j] & 0xffffu)) + ah[k8 + j * 2]), vs[k8 + j * 2], sA);
            sA = fmaf(tanhf(bf2f((ushort)(u[j] >> 16)) + ah[k8 + j * 2 + 1]), vs[k8 + j * 2 + 1], sA);
          }
        }
        if (vB) {
          const unsigned u[4] = {vb2.x, vb2.y, vb2.z, vb2.w};
#pragma unroll
          for (int j = 0; j < 4; ++j) {
            sB = fmaf(tanhf(bf2f((ushort)(u[j] & 0xffffu)) + ah[k8 + j * 2]), vs[k8 + j * 2], sB);
            sB = fmaf(tanhf(bf2f((ushort)(u[j] >> 16)) + ah[k8 + j * 2 + 1]), vs[k8 + j * 2 + 1], sB);
          }
        }
#pragma unroll
        for (int off = 32; off > 0; off >>= 1) {
          sA += __shfl_xor(sA, off); sB += __shfl_xor(sB, off);
        }
        if (lane == 0) {
          if (vA) p.ev_g[b * 256 + pA] = sA + bv;
          if (vB) p.ev_g[b * 256 + pB] = sB + bv;
        }
      }
      __syncthreads();
    }
    gsync(p.bar);

    // ---- PB2: softmax (redundant x4) + gated context, 4-deep p-unroll ----
    {
      const int b = blk >> 2, sl = blk & 3;
      float* pc = scr;            // 4096
      float* al = scr + 4096;     // 196
      float* red = scr + 4352;    // 256
      float x = (tid < Pq) ? p.ev_g[b * 256 + tid] : -INFINITY;
      if (tid < 256) red[tid] = x;
      __syncthreads();
      for (int s2 = 128; s2 > 0; s2 >>= 1) {
        if (tid < s2) red[tid] = fmaxf(red[tid], red[tid + s2]);
        __syncthreads();
      }
      float mx = red[0];
      __syncthreads();
      float ex = (tid < Pq) ? expf(x - mx) : 0.f;
      if (tid < 256) red[tid] = ex;
      __syncthreads();
      for (int s2 = 128; s2 > 0; s2 >>= 1) {
        if (tid < s2) red[tid] += red[tid + s2];
        __syncthreads();
      }
      float inv = 1.f / red[0];
      if (tid < Pq) {
        float a = ex * inv;
        al[tid] = a;
        if (sl == 0) p.alphas_out[((size_t)b * Tq + t) * Pq + tid] = a;
      }
      __syncthreads();
      // context: 512-d slice, 8-way p-split, 4 independent loads in flight
      const int tid2 = tid & 127, ph = tid >> 7;
      const int d4 = tid2 * 4, d = sl * 512 + d4;
      const int pb2 = (ph * 196) >> 3, pe2 = ((ph + 1) * 196) >> 3;
      const ushort* ib = p.img16 + (size_t)b * Pq * Dq + d;
      float s0 = 0.f, s1 = 0.f, s2a = 0.f, s3 = 0.f;
      int pp = pb2;
      for (; pp + 4 <= pe2; pp += 4) {
        uint2 v0 = *reinterpret_cast<const uint2*>(ib + (size_t)(pp + 0) * Dq);
        uint2 v1 = *reinterpret_cast<const uint2*>(ib + (size_t)(pp + 1) * Dq);
        uint2 v2 = *reinterpret_cast<const uint2*>(ib + (size_t)(pp + 2) * Dq);
        uint2 v3 = *reinterpret_cast<const uint2*>(ib + (size_t)(pp + 3) * Dq);
        float a0 = al[pp], a1 = al[pp + 1], a2 = al[pp + 2], a3 = al[pp + 3];
        s0 = fmaf(a0, bf2f((ushort)(v0.x & 0xffffu)), s0);
        s1 = fmaf(a0, bf2f((ushort)(v0.x >> 16)), s1);
        s2a = fmaf(a0, bf2f((ushort)(v0.y & 0xffffu)), s2a);
        s3 = fmaf(a0, bf2f((ushort)(v0.y >> 16)), s3);
        s0 = fmaf(a1, bf2f((ushort)(v1.x & 0xffffu)), s0);
        s1 = fmaf(a1, bf2f((ushort)(v1.x >> 16)), s1);
        s2a = fmaf(a1, bf2f((ushort)(v1.y & 0xffffu)), s2a);
        s3 = fmaf(a1, bf2f((ushort)(v1.y >> 16)), s3);
        s0 = fmaf(a2, bf2f((ushort)(v2.x & 0xffffu)), s0);
        s1 = fmaf(a2, bf2f((ushort)(v2.x >> 16)), s1);
        s2a = fmaf(a2, bf2f((ushort)(v2.y & 0xffffu)), s2a);
        s3 = fmaf(a2, bf2f((ushort)(v2.y >> 16)), s3);
        s0 = fmaf(a3, bf2f((ushort)(v3.x & 0xffffu)), s0);
        s1 = fmaf(a3, bf2f((ushort)(v3.x >> 16)), s1);
        s2a = fmaf(a3, bf2f((ushort)(v3.y & 0xffffu)), s2a);
        s3 = fmaf(a3, bf2f((ushort)(v3.y >> 16)), s3);
      }
      for (; pp < pe2; ++pp) {
        uint2 v = *reinterpret_cast<const uint2*>(ib + (size_t)pp * Dq);
        float a = al[pp];
        s0 = fmaf(a, bf2f((ushort)(v.x & 0xffffu)), s0);
        s1 = fmaf(a, bf2f((ushort)(v.x >> 16)), s1);
        s2a = fmaf(a, bf2f((ushort)(v.y & 0xffffu)), s2a);
        s3 = fmaf(a, bf2f((ushort)(v.y >> 16)), s3);
      }
      pc[ph * 512 + d4 + 0] = s0; pc[ph * 512 + d4 + 1] = s1;
      pc[ph * 512 + d4 + 2] = s2a; pc[ph * 512 + d4 + 3] = s3;
      __syncthreads();
      if (tid < 512) {
        float sum = 0.f;
#pragma unroll
        for (int q = 0; q < 8; ++q) sum += pc[q * 512 + tid];
        int dd = sl * 512 + tid;
        float g = sigf(p.b_fbeta[dd] + p.Pfb[(size_t)b * Dq + dd]
                       + p.Pfb[(size_t)Bq * Dq + b * Dq + dd]);
        p.ctxg[(size_t)b * Dq + dd] = sum * g;
      }
      __syncthreads();
    }
    gsync(p.bar);

    // ---- PC: ctx-gates GEMM partials (all 256 blocks, LDS-W) ----
    {
      float acc[4] = {};
      gemm_ldsw<0>(p.ctxg, Dq, ksc * 256, WsCtx, nullptr, nullptr, t, As, tid, acc);
      float* Pout = p.Pg + (size_t)ksc * Bq * Dq;
#pragma unroll
      for (int ni = 0; ni < 4; ++ni)
        Pout[(size_t)ty * Dq + n0c + tx * 4 + ni] = acc[ni];
    }
    gsync(p.bar);

    // ---- PD: LSTM epilogue (32 blocks x 1024 threads) ----
    if (blk < 32) {
      int idx = blk * 1024 + tid;
      int b = idx >> 9, e = idx & 511;
      float g0 = p.b_ih[e] + p.b_hh[e];
      float g1 = p.b_ih[Eq + e] + p.b_hh[Eq + e];
      float g2 = p.b_ih[2 * Eq + e] + p.b_hh[2 * Eq + e];
      float g3 = p.b_ih[3 * Eq + e] + p.b_hh[3 * Eq + e];
#pragma unroll
      for (int s = 0; s < 2; ++s) {
        const float* Pr = p.Pwh + ((size_t)s * Bq + b) * Dq;
        g0 += Pr[e]; g1 += Pr[Eq + e]; g2 += Pr[2 * Eq + e]; g3 += Pr[3 * Eq + e];
      }
#pragma unroll
      for (int s = 0; s < 2; ++s) {
        const float* Pr = p.Pge + ((size_t)s * Bq + b) * Dq;
        g0 += Pr[e]; g1 += Pr[Eq + e]; g2 += Pr[2 * Eq + e]; g3 += Pr[3 * Eq + e];
      }
#pragma unroll
      for (int s = 0; s < 8; ++s) {
        const float* Pr = p.Pg + ((size_t)s * Bq + b) * Dq;
        g0 += Pr[e]; g1 += Pr[Eq + e]; g2 += Pr[2 * Eq + e]; g3 += Pr[3 * Eq + e];
      }
      float ig = sigf(g0), fg = sigf(g1), gg = tanhf(g2), og = sigf(g3);
      float cn = fg * p.c[idx] + ig * gg;
      p.c[idx] = cn;
      p.hseq[(size_t)t * Bq * Eq + idx] = og * tanhf(cn);
    }
    gsync(p.bar);
  }
}

// ---------------- final batched preds GEMM (fp32, BM=128 BN=64) ----------------
__global__ __launch_bounds__(256) void gemm_out_big(const float* __restrict__ hseq,
                                                    const float* __restrict__ W_out,
                                                    const float* __restrict__ b_out,
                                                    float* __restrict__ out) {
  __shared__ float As[32][132];
  __shared__ float Ws[32][68];
  const int tid = threadIdx.x;
  const int tx = tid & 15, ty = tid >> 4;
  const int m0 = blockIdx.x * 128, n0 = blockIdx.y * 64;
  float acc[8][4] = {};
  for (int k0 = 0; k0 < Eq; k0 += 32) {
#pragma unroll
    for (int i = 0; i < 4; ++i) {
      int idx = tid + i * 256;
      int r = idx >> 3, c = (idx & 7) << 2;
      const float4 a = *reinterpret_cast<const float4*>(hseq + (size_t)(m0 + r) * Eq + k0 + c);
      As[c + 0][r] = a.x; As[c + 1][r] = a.y; As[c + 2][r] = a.z; As[c + 3][r] = a.w;
    }
#pragma unroll
    for (int i = 0; i < 2; ++i) {
      int idx = tid + i * 256;
      int r = idx >> 3, c = (idx & 7) << 2;
      int wr2 = n0 + r; if (wr2 >= Vq) wr2 = Vq - 1;
      const float4 w = *reinterpret_cast<const float4*>(W_out + (size_t)wr2 * Eq + k0 + c);
      Ws[c + 0][r] = w.x; Ws[c + 1][r] = w.y; Ws[c + 2][r] = w.z; Ws[c + 3][r] = w.w;
    }
    __syncthreads();
#pragma unroll
    for (int k = 0; k < 32; ++k) {
      float a[8], w[4];
#pragma unroll
      for (int i = 0; i < 8; ++i) a[i] = As[k][ty * 8 + i];
#pragma unroll
      for (int j = 0; j < 4; ++j) w[j] = Ws[k][tx * 4 + j];
#pragma unroll
      for (int i = 0; i < 8; ++i)
#pragma unroll
        for (int j = 0; j < 4; ++j) acc[i][j] = fmaf(a[i], w[j], acc[i][j]);
    }
    __syncthreads();
  }
#pragma unroll
  for (int j = 0; j < 4; ++j) {
    int n = n0 + tx * 4 + j;
    if (n < Vq) {
      float bv = b_out[n];
#pragma unroll
      for (int i = 0; i < 8; ++i) {
        int m = m0 + ty * 8 + i;
        int t = m >> 6, b = m & 63;
        out[((size_t)b * Tq + t) * Vq + n] = acc[i][j] + bv;
      }
    }
  }
}

}  // namespace

extern "C" void kernel_launch(void* const* d_in, const int* in_sizes, int n_in,
                              void* d_out, int out_size, void* d_ws, size_t ws_size,
                              hipStream_t stream) {
  (void)in_sizes; (void)n_in; (void)out_size; (void)ws_size;
  const float* img      = (const float*)d_in[0];
  const int*   caps     = (const int*)d_in[1];
  const float* emb      = (const float*)d_in[2];
  const float* W_init_h = (const float*)d_in[3];
  const float* b_init_h = (const float*)d_in[4];
  const float* W_init_c = (const float*)d_in[5];
  const float* b_init_c = (const float*)d_in[6];
  const float* W_fbeta  = (const float*)d_in[7];
  const float* b_fbeta  = (const float*)d_in[8];
  const float* U_att    = (const float*)d_in[9];
  const float* b_Uatt   = (const float*)d_in[10];
  const float* W_att    = (const float*)d_in[11];
  const float* b_Watt   = (const float*)d_in[12];
  const float* v_att    = (const float*)d_in[13];
  const float* b_vatt   = (const float*)d_in[14];
  const float* W_ih     = (const float*)d_in[15];
  const float* b_ih     = (const float*)d_in[16];
  const float* W_hh     = (const float*)d_in[17];
  const float* b_hh     = (const float*)d_in[18];
  const float* W_out    = (const float*)d_in[19];
  const float* b_out    = (const float*)d_in[20];

  float* out = (float*)d_out;
  float* alphas_out = out + (size_t)Bq * Tq * Vq;

  float* ws = (float*)d_ws;
  ushort* img16   = (ushort*)ws; ws += N_IMG / 2;
  ushort* Watt16  = (ushort*)ws; ws += ((size_t)Eq * Dq) / 2;
  ushort* fproj16 = (ushort*)ws; ws += ((size_t)Bq * Pq * Eq) / 2;
  float* hseq  = ws; ws += (size_t)Tq * Bq * Eq;
  float* h0    = ws; ws += Bq * Eq;
  float* c     = ws; ws += Bq * Eq;
  float* ctxg  = ws; ws += Bq * Dq;
  float* ev_g  = ws; ws += Bq * 256;
  float* Pah   = ws; ws += (size_t)2 * Bq * Eq;
  float* Pfb   = ws; ws += (size_t)2 * Bq * Dq;
  float* Pwh   = ws; ws += (size_t)2 * Bq * Dq;
  float* Pge   = ws; ws += (size_t)2 * Bq * Dq;
  float* Pg    = ws; ws += (size_t)8 * Bq * Dq;
  float* avg   = ws; ws += Bq * Dq;
  float* initP = ws; ws += (size_t)16 * Bq * Eq;
  unsigned* bar = (unsigned*)ws; ws += 256;

  // ---- prolog ----
  bar_init<<<1, 256, 0, stream>>>(bar);
  cvt_all<<<(int)((N_IMG / 8 + (size_t)Eq * Dq / 8) / 256), 256, 0, stream>>>(img, W_att, img16,
                                                                              Watt16);
  avg_kernel<<<Bq * Dq / 256, 256, 0, stream>>>(img, avg);
  init_partial<<<dim3(8, 8, 2), 256, 0, stream>>>(avg, W_init_h, W_init_c, initP);
  init_epi<<<2 * Bq * Eq / 256, 256, 0, stream>>>(initP, b_init_h, b_init_c, h0, c);
  fproj_mfma<<<dim3(Bq * Pq / 128, Eq / 64), 256, 0, stream>>>(img16, Watt16, b_Watt, fproj16);

  // ---- 32-step recurrence: persistent kernel, 5 phases/step ----
  StepParams sp;
  sp.caps = caps; sp.emb = emb; sp.U_att = U_att; sp.b_Uatt = b_Uatt;
  sp.W_fbeta = W_fbeta; sp.b_fbeta = b_fbeta; sp.v_att = v_att; sp.b_vatt = b_vatt;
  sp.W_ih = W_ih; sp.b_ih = b_ih; sp.W_hh = W_hh; sp.b_hh = b_hh;
  sp.img16 = img16; sp.fproj16 = fproj16; sp.h0 = h0;
  sp.c = c; sp.hseq = hseq; sp.ctxg = ctxg; sp.ev_g = ev_g;
  sp.Pah = Pah; sp.Pfb = Pfb; sp.Pwh = Pwh; sp.Pge = Pge; sp.Pg = Pg;
  sp.alphas_out = alphas_out; sp.bar = bar;
  step_loop<<<NBLK, 1024, 0, stream>>>(sp);

  // ---- batched preds GEMM ----
  gemm_out_big<<<dim3(Tq * Bq / 128, 157), 256, 0, stream>>>(hseq, W_out, b_out, out);
}

// Round 16
// 4487.907 us; speedup vs baseline: 1.0066x; 1.0066x over previous
//
#include <hip/hip_runtime.h>
#include <math.h>

namespace {

constexpr int Bq = 64, Pq = 196, Dq = 2048, Eq = 512, Vq = 10000, Tq = 32, T1q = 33;
constexpr size_t N_IMG = (size_t)Bq * Pq * Dq;  // 25,690,112
constexpr int NBLK = 256;

typedef __attribute__((ext_vector_type(8))) short bf16x8;
typedef __attribute__((ext_vector_type(4))) float f32x4;

__device__ __forceinline__ float sigf(float x) { return 1.f / (1.f + expf(-x)); }

__device__ __forceinline__ ushort f2bf(float f) {
  union { float f; unsigned u; } v; v.f = f;
  unsigned u = v.u;
  return (ushort)((u + 0x7fffu + ((u >> 16) & 1u)) >> 16);  // RNE
}
__device__ __forceinline__ float bf2f(ushort h) {
  union { unsigned u; float f; } v; v.u = ((unsigned)h) << 16;
  return v.f;
}

// ---- grid barrier (R10-proven) ----
__device__ __forceinline__ void gsync(unsigned* bar) {
  __syncthreads();
  if (threadIdx.x == 0) {
    __builtin_amdgcn_fence(__ATOMIC_RELEASE, "agent");
    unsigned g = __hip_atomic_load(&bar[144], __ATOMIC_RELAXED, __HIP_MEMORY_SCOPE_AGENT);
    unsigned shard = ((unsigned)blockIdx.x & 7u) * 16u;
    unsigned a = __hip_atomic_fetch_add(&bar[shard], 1u, __ATOMIC_RELAXED,
                                        __HIP_MEMORY_SCOPE_AGENT);
    if (a == 31u) {
      unsigned tot = __hip_atomic_fetch_add(&bar[128], 32u, __ATOMIC_RELAXED,
                                            __HIP_MEMORY_SCOPE_AGENT);
      if (tot == (unsigned)NBLK - 32u) {
        for (unsigned i = 0; i < 8; ++i)
          __hip_atomic_store(&bar[i * 16u], 0u, __ATOMIC_RELAXED, __HIP_MEMORY_SCOPE_AGENT);
        __hip_atomic_store(&bar[128], 0u, __ATOMIC_RELAXED, __HIP_MEMORY_SCOPE_AGENT);
        __hip_atomic_store(&bar[144], g + 1u, __ATOMIC_RELEASE, __HIP_MEMORY_SCOPE_AGENT);
      }
    }
    while (__hip_atomic_load(&bar[144], __ATOMIC_RELAXED, __HIP_MEMORY_SCOPE_AGENT) == g) {
      __builtin_amdgcn_s_sleep(1);
    }
    __builtin_amdgcn_fence(__ATOMIC_ACQUIRE, "agent");
  }
  __syncthreads();
}

__global__ void bar_init(unsigned* bar) { bar[threadIdx.x] = 0u; }

// ---------------- prolog kernels (unchanged) ----------------

__global__ __launch_bounds__(256) void cvt_all(const float* __restrict__ img,
                                               const float* __restrict__ Watt,
                                               ushort* __restrict__ img16,
                                               ushort* __restrict__ Watt16) {
  int u = blockIdx.x * 256 + threadIdx.x;
  constexpr int NU_IMG = (int)(N_IMG / 8);
  const float* src; ushort* dst; int off;
  if (u < NU_IMG) { src = img; dst = img16; off = u; }
  else { src = Watt; dst = Watt16; off = u - NU_IMG; }
  const float4 a = reinterpret_cast<const float4*>(src)[2 * (size_t)off];
  const float4 b = reinterpret_cast<const float4*>(src)[2 * (size_t)off + 1];
  union { ushort s[8]; uint4 v; } o;
  o.s[0] = f2bf(a.x); o.s[1] = f2bf(a.y); o.s[2] = f2bf(a.z); o.s[3] = f2bf(a.w);
  o.s[4] = f2bf(b.x); o.s[5] = f2bf(b.y); o.s[6] = f2bf(b.z); o.s[7] = f2bf(b.w);
  reinterpret_cast<uint4*>(dst)[off] = o.v;
}

__global__ __launch_bounds__(256) void avg_kernel(const float* __restrict__ img,
                                                  float* __restrict__ avg) {
  int idx = blockIdx.x * 256 + threadIdx.x;
  int b = idx >> 11, d = idx & (Dq - 1);
  const float* ib = img + (size_t)b * Pq * Dq + d;
  float s = 0.f;
  for (int p = 0; p < Pq; ++p) s += ib[(size_t)p * Dq];
  avg[idx] = s * (1.f / Pq);
}

__global__ __launch_bounds__(256) void init_partial(const float* __restrict__ avg,
                                                    const float* __restrict__ Wh,
                                                    const float* __restrict__ Wc,
                                                    float* __restrict__ P) {
  __shared__ float smem[4224];
  float (*As)[66] = reinterpret_cast<float(*)[66]>(smem);
  float (*Ws)[66] = reinterpret_cast<float(*)[66]>(smem + 32 * 66);
  const float* W = blockIdx.z ? Wc : Wh;
  float* Pout = P + (size_t)blockIdx.z * 8 * Bq * Eq + (size_t)blockIdx.y * Bq * Eq;
  const int tid = threadIdx.x;
  const int tx = tid & 15, ty = tid >> 4;
  const int n0 = blockIdx.x * 64, kbeg = blockIdx.y * 256;
  float acc[4][4] = {};
  for (int it = 0; it < 8; ++it) {
    const int k0 = kbeg + it * 32;
#pragma unroll
    for (int i = 0; i < 2; ++i) {
      int idx = tid + i * 256, r = idx >> 3, c = (idx & 7) << 2;
      const float4 a = *reinterpret_cast<const float4*>(avg + (size_t)r * Dq + k0 + c);
      As[c + 0][r] = a.x; As[c + 1][r] = a.y; As[c + 2][r] = a.z; As[c + 3][r] = a.w;
      const float4 w = *reinterpret_cast<const float4*>(W + (size_t)(n0 + r) * Dq + k0 + c);
      Ws[c + 0][r] = w.x; Ws[c + 1][r] = w.y; Ws[c + 2][r] = w.z; Ws[c + 3][r] = w.w;
    }
    __syncthreads();
#pragma unroll
    for (int k = 0; k < 32; ++k) {
      float av[4], wv[4];
#pragma unroll
      for (int i2 = 0; i2 < 4; ++i2) { av[i2] = As[k][ty * 4 + i2]; wv[i2] = Ws[k][tx * 4 + i2]; }
#pragma unroll
      for (int mi = 0; mi < 4; ++mi)
#pragma unroll
        for (int ni = 0; ni < 4; ++ni) acc[mi][ni] = fmaf(av[mi], wv[ni], acc[mi][ni]);
    }
    __syncthreads();
  }
#pragma unroll
  for (int ni = 0; ni < 4; ++ni)
#pragma unroll
    for (int mi = 0; mi < 4; ++mi)
      Pout[(size_t)(ty * 4 + mi) * Eq + n0 + tx * 4 + ni] = acc[mi][ni];
}

__global__ __launch_bounds__(256) void init_epi(const float* __restrict__ P,
                                                const float* __restrict__ b_h,
                                                const float* __restrict__ b_c,
                                                float* __restrict__ h0,
                                                float* __restrict__ c) {
  int idx = blockIdx.x * 256 + threadIdx.x;
  int which = idx >> 15, j = idx & 32767;
  int b = j >> 9, e = j & 511;
  const float* Pp = P + (size_t)which * 8 * Bq * Eq;
  float s = which ? b_c[e] : b_h[e];
#pragma unroll
  for (int sp = 0; sp < 8; ++sp) s += Pp[((size_t)sp * Bq + b) * Eq + e];
  float v = tanhf(s);
  if (which) c[j] = v; else h0[j] = v;
}

// fproj16 = bf16(img16 @ Watt16^T + b_Watt) via bf16 MFMA. grid (98, 8).
__global__ __launch_bounds__(256) void fproj_mfma(const ushort* __restrict__ A16,
                                                  const ushort* __restrict__ B16,
                                                  const float* __restrict__ bias,
                                                  ushort* __restrict__ C16) {
  __shared__ ushort As[128 * 32];
  __shared__ ushort Bs[64 * 32];
  const int tid = threadIdx.x;
  const int lane = tid & 63, wave = tid >> 6;
  const int m0 = blockIdx.x * 128, n0 = blockIdx.y * 64;
  const int wr = (wave >> 1) * 64, wc = (wave & 1) * 32;
  f32x4 acc[4][2] = {};
  const int ar = tid >> 1, seg = (tid & 1) * 16;
  const int br = (tid & 127) >> 1;
  for (int k0 = 0; k0 < Dq; k0 += 32) {
    const ushort* ga = A16 + (size_t)(m0 + ar) * Dq + k0 + seg;
    uint4 a0 = *reinterpret_cast<const uint4*>(ga);
    uint4 a1 = *reinterpret_cast<const uint4*>(ga + 8);
    unsigned ab = (unsigned)(ar * 64 + seg * 2);
    unsigned sw = (unsigned)((ar & 7) << 4);
    *reinterpret_cast<uint4*>(reinterpret_cast<char*>(As) + (ab ^ sw)) = a0;
    *reinterpret_cast<uint4*>(reinterpret_cast<char*>(As) + ((ab + 16) ^ sw)) = a1;
    if (tid < 128) {
      const ushort* gb = B16 + (size_t)(n0 + br) * Dq + k0 + seg;
      uint4 b0 = *reinterpret_cast<const uint4*>(gb);
      uint4 b1 = *reinterpret_cast<const uint4*>(gb + 8);
      unsigned bb = (unsigned)(br * 64 + seg * 2);
      unsigned sb = (unsigned)((br & 7) << 4);
      *reinterpret_cast<uint4*>(reinterpret_cast<char*>(Bs) + (bb ^ sb)) = b0;
      *reinterpret_cast<uint4*>(reinterpret_cast<char*>(Bs) + ((bb + 16) ^ sb)) = b1;
    }
    __syncthreads();
    const int g = lane >> 4;
    bf16x8 af[4], bfr[2];
#pragma unroll
    for (int i = 0; i < 4; ++i) {
      int row = wr + i * 16 + (lane & 15);
      af[i] = *reinterpret_cast<const bf16x8*>(
          reinterpret_cast<char*>(As) + ((unsigned)(row * 64 + g * 16) ^ ((row & 7) << 4)));
    }
#pragma unroll
    for (int j = 0; j < 2; ++j) {
      int col = wc + j * 16 + (lane & 15);
      bfr[j] = *reinterpret_cast<const bf16x8*>(
          reinterpret_cast<char*>(Bs) + ((unsigned)(col * 64 + g * 16) ^ ((col & 7) << 4)));
    }
#pragma unroll
    for (int i = 0; i < 4; ++i)
#pragma unroll
      for (int j = 0; j < 2; ++j)
        acc[i][j] = __builtin_amdgcn_mfma_f32_16x16x32_bf16(af[i], bfr[j], acc[i][j], 0, 0, 0);
    __syncthreads();
  }
#pragma unroll
  for (int i = 0; i < 4; ++i) {
#pragma unroll
    for (int j = 0; j < 2; ++j) {
      int n = n0 + wc + j * 16 + (lane & 15);
      float bv = bias[n];
#pragma unroll
      for (int q = 0; q < 4; ++q) {
        int m = m0 + wr + i * 16 + (lane >> 4) * 4 + q;
        C16[(size_t)m * Eq + n] = f2bf(acc[i][j][q] + bv);
      }
    }
  }
}

// ---------------- persistent step-loop ----------------

struct StepParams {
  const int* caps;
  const float* emb;
  const float* U_att;
  const float* b_Uatt;
  const float* W_fbeta;
  const float* b_fbeta;
  const float* v_att;
  const float* b_vatt;
  const float* W_ih;
  const float* b_ih;
  const float* W_hh;
  const float* b_hh;
  const ushort* img16;
  const ushort* fproj16;
  const float* h0;
  float* c;
  float* hseq;
  float* ctxg;
  float* ev_g;
  float* Pah;
  float* Pfb;
  float* Pwh;
  float* Pge;
  float* Pg;
  float* alphas_out;
  unsigned* bar;
};

// 64x64 out tile over a K=256 slice; W in LDS bf16; 1024 threads, acc[4].
template <int MODE>
__device__ __forceinline__ void gemm_ldsw(
    const float* __restrict__ A, int lda, int kbase,
    const ushort (* __restrict__ Ws)[64],
    const float* __restrict__ emb, const int* __restrict__ caps, int t,
    float (*As)[66], int tid, float acc[4]) {
  const int tx = tid & 15, ty = tid >> 4;
  const int cc = (tid & 15) * 2;
  float2 pa;
  auto loadA = [&](int kc) {
    if (MODE == 1) {
      int tok = caps[ty * T1q + t];
      pa = *reinterpret_cast<const float2*>(emb + (size_t)tok * Eq + kbase + kc * 32 + cc);
    } else {
      pa = *reinterpret_cast<const float2*>(A + (size_t)ty * lda + kbase + kc * 32 + cc);
    }
  };
  loadA(0);
  for (int kc = 0; kc < 8; ++kc) {
    As[cc + 0][ty] = pa.x; As[cc + 1][ty] = pa.y;
    __syncthreads();
    if (kc < 7) loadA(kc + 1);
#pragma unroll
    for (int k = 0; k < 32; ++k) {
      float av = As[k][ty];
      uint2 wu = *reinterpret_cast<const uint2*>(&Ws[kc * 32 + k][tx * 4]);
      acc[0] = fmaf(av, bf2f((ushort)(wu.x & 0xffffu)), acc[0]);
      acc[1] = fmaf(av, bf2f((ushort)(wu.x >> 16)), acc[1]);
      acc[2] = fmaf(av, bf2f((ushort)(wu.y & 0xffffu)), acc[2]);
      acc[3] = fmaf(av, bf2f((ushort)(wu.y >> 16)), acc[3]);
    }
    __syncthreads();
  }
}

__global__ __launch_bounds__(1024) void step_loop(StepParams p) {
  __shared__ ushort WsRole[256][64];   // 32 KB
  __shared__ ushort WsCtx[256][64];    // 32 KB
  __shared__ ushort Fs[49 * 512];      // 50 KB: this block's fproj slice (rows pbeg..pbeg+48)
  __shared__ float As[32][66];         // 8.25 KB
  __shared__ float scr[4608];          // 18 KB
  const int blk = blockIdx.x;
  const int tid = threadIdx.x;

  // ---- stage weights + fproj slice to LDS once ----
  {
    const float* Wsrc = nullptr; int n0 = 0, koff = 0, ld = Eq;
    if (blk < 16)       { Wsrc = p.U_att;   n0 = (blk & 7) * 64;  koff = (blk >> 3) * 256; }
    else if (blk < 80)  { int i2 = blk - 16;  Wsrc = p.W_fbeta; n0 = (i2 & 31) * 64; koff = (i2 >> 5) * 256; }
    else if (blk < 144) { int i2 = blk - 80;  Wsrc = p.W_hh;    n0 = (i2 & 31) * 64; koff = (i2 >> 5) * 256; }
    else if (blk < 208) { int i2 = blk - 144; Wsrc = p.W_ih;    n0 = (i2 & 31) * 64; koff = (i2 >> 5) * 256; ld = Eq + Dq; }
    if (Wsrc) {
      for (int i = tid; i < 4096; i += 1024) {
        int r = i >> 6, c4 = (i & 63) << 2;
        const float4 w = *reinterpret_cast<const float4*>(Wsrc + (size_t)(n0 + r) * ld + koff + c4);
        WsRole[c4 + 0][r] = f2bf(w.x); WsRole[c4 + 1][r] = f2bf(w.y);
        WsRole[c4 + 2][r] = f2bf(w.z); WsRole[c4 + 3][r] = f2bf(w.w);
      }
    }
    int n0c = (blk & 31) * 64, kc = (blk >> 5) * 256;
    for (int i = tid; i < 4096; i += 1024) {
      int r = i >> 6, c4 = (i & 63) << 2;
      const float4 w = *reinterpret_cast<const float4*>(
          p.W_ih + (size_t)(n0c + r) * (Eq + Dq) + Eq + kc + c4);
      WsCtx[c4 + 0][r] = f2bf(w.x); WsCtx[c4 + 1][r] = f2bf(w.y);
      WsCtx[c4 + 2][r] = f2bf(w.z); WsCtx[c4 + 3][r] = f2bf(w.w);
    }
    // fproj slice: b = blk>>2, rows (blk&3)*49 .. +49
    const int fb = blk >> 2, fp0 = (blk & 3) * 49;
    const ushort* src = p.fproj16 + ((size_t)fb * Pq + fp0) * Eq;
    for (int i = tid; i < 49 * 512 / 8; i += 1024) {
      reinterpret_cast<uint4*>(Fs)[i] = reinterpret_cast<const uint4*>(src)[i];
    }
    __syncthreads();
  }

  const int tx = tid & 15, ty = tid >> 4;
  const int n0c = (blk & 31) * 64, ksc = blk >> 5;

  for (int t = 0; t < Tq; ++t) {
    const float* hc = (t == 0) ? p.h0 : p.hseq + (size_t)(t - 1) * Bq * Eq;

    // ---- PA: att_h | fbeta | Whh | emb-gates (LDS-W GEMM partials) ----
    if (blk < 208) {
      float acc[4] = {};
      float* Pout; int n0, Npad;
      if (blk < 16) {
        int ks = blk >> 3; n0 = (blk & 7) * 64; Npad = Eq;
        gemm_ldsw<0>(hc, Eq, ks * 256, WsRole, nullptr, nullptr, t, As, tid, acc);
        Pout = p.Pah + (size_t)ks * Bq * Eq;
      } else if (blk < 80) {
        int i2 = blk - 16, ks = i2 >> 5; n0 = (i2 & 31) * 64; Npad = Dq;
        gemm_ldsw<0>(hc, Eq, ks * 256, WsRole, nullptr, nullptr, t, As, tid, acc);
        Pout = p.Pfb + (size_t)ks * Bq * Dq;
      } else if (blk < 144) {
        int i2 = blk - 80, ks = i2 >> 5; n0 = (i2 & 31) * 64; Npad = Dq;
        gemm_ldsw<0>(hc, Eq, ks * 256, WsRole, nullptr, nullptr, t, As, tid, acc);
        Pout = p.Pwh + (size_t)ks * Bq * Dq;
      } else {
        int i2 = blk - 144, ks = i2 >> 5; n0 = (i2 & 31) * 64; Npad = Dq;
        gemm_ldsw<1>(nullptr, 0, ks * 256, WsRole, p.emb, p.caps, t, As, tid, acc);
        Pout = p.Pge + (size_t)ks * Bq * Dq;
      }
#pragma unroll
      for (int ni = 0; ni < 4; ++ni)
        Pout[(size_t)ty * Npad + n0 + tx * 4 + ni] = acc[ni];
    }
    gsync(p.bar);

    // ---- PB1: e-scores from LDS fproj slice (49 p's, 16 waves) ----
    {
      const int b = blk >> 2, pq = blk & 3;
      const int lane = tid & 63, wv = tid >> 6;
      float* ah = scr; float* vs = scr + 512;
      if (tid < Eq) {
        ah[tid] = p.b_Uatt[tid] + p.Pah[(size_t)b * Eq + tid]
                + p.Pah[(size_t)Bq * Eq + b * Eq + tid];
        vs[tid] = p.v_att[tid];
      }
      __syncthreads();
      const float bv = p.b_vatt[0];
      const int pbeg = pq * 49;
      const int k8 = lane * 8;
      for (int pl = wv; pl < 49; pl += 16) {
        const ushort* f0 = Fs + pl * Eq + k8;
        uint4 va = *reinterpret_cast<const uint4*>(f0);
        float s = 0.f;
        const unsigned u[4] = {va.x, va.y, va.z, va.w};
#pragma unroll
        for (int j = 0; j < 4; ++j) {
          s = fmaf(tanhf(bf2f((ushort)(u[j] & 0xffffu)) + ah[k8 + j * 2]), vs[k8 + j * 2], s);
          s = fmaf(tanhf(bf2f((ushort)(u[j] >> 16)) + ah[k8 + j * 2 + 1]), vs[k8 + j * 2 + 1], s);
        }
#pragma unroll
        for (int off = 32; off > 0; off >>= 1) s += __shfl_xor(s, off);
        if (lane == 0) p.ev_g[b * 256 + pbeg + pl] = s + bv;
      }
      __syncthreads();
    }
    gsync(p.bar);

    // ---- PB2: softmax (redundant x4) + gated context 512-d slice (R14 loop) ----
    {
      const int b = blk >> 2, sl = blk & 3;
      float* pc = scr;            // 4096
      float* al = scr + 4096;     // 196
      float* red = scr + 4352;    // 256
      float x = (tid < Pq) ? p.ev_g[b * 256 + tid] : -INFINITY;
      if (tid < 256) red[tid] = x;
      __syncthreads();
      for (int s2 = 128; s2 > 0; s2 >>= 1) {
        if (tid < s2) red[tid] = fmaxf(red[tid], red[tid + s2]);
        __syncthreads();
      }
      float mx = red[0];
      __syncthreads();
      float ex = (tid < Pq) ? expf(x - mx) : 0.f;
      if (tid < 256) red[tid] = ex;
      __syncthreads();
      for (int s2 = 128; s2 > 0; s2 >>= 1) {
        if (tid < s2) red[tid] += red[tid + s2];
        __syncthreads();
      }
      float inv = 1.f / red[0];
      if (tid < Pq) {
        float a = ex * inv;
        al[tid] = a;
        if (sl == 0) p.alphas_out[((size_t)b * Tq + t) * Pq + tid] = a;
      }
      __syncthreads();
      const int tid2 = tid & 127, ph = tid >> 7;
      const int d4 = tid2 * 4, d = sl * 512 + d4;
      const int pb2 = (ph * 196) >> 3, pe2 = ((ph + 1) * 196) >> 3;
      const ushort* ib = p.img16 + (size_t)b * Pq * Dq + d;
      float s0 = 0.f, s1 = 0.f, s2a = 0.f, s3 = 0.f;
      for (int pp = pb2; pp < pe2; ++pp) {
        uint2 v = *reinterpret_cast<const uint2*>(ib + (size_t)pp * Dq);
        float a = al[pp];
        s0 = fmaf(a, bf2f((ushort)(v.x & 0xffffu)), s0);
        s1 = fmaf(a, bf2f((ushort)(v.x >> 16)), s1);
        s2a = fmaf(a, bf2f((ushort)(v.y & 0xffffu)), s2a);
        s3 = fmaf(a, bf2f((ushort)(v.y >> 16)), s3);
      }
      pc[ph * 512 + d4 + 0] = s0; pc[ph * 512 + d4 + 1] = s1;
      pc[ph * 512 + d4 + 2] = s2a; pc[ph * 512 + d4 + 3] = s3;
      __syncthreads();
      if (tid < 512) {
        float sum = 0.f;
#pragma unroll
        for (int q = 0; q < 8; ++q) sum += pc[q * 512 + tid];
        int dd = sl * 512 + tid;
        float g = sigf(p.b_fbeta[dd] + p.Pfb[(size_t)b * Dq + dd]
                       + p.Pfb[(size_t)Bq * Dq + b * Dq + dd]);
        p.ctxg[(size_t)b * Dq + dd] = sum * g;
      }
      __syncthreads();
    }
    gsync(p.bar);

    // ---- PC: ctx-gates GEMM partials (all 256 blocks, LDS-W) ----
    {
      float acc[4] = {};
      gemm_ldsw<0>(p.ctxg, Dq, ksc * 256, WsCtx, nullptr, nullptr, t, As, tid, acc);
      float* Pout = p.Pg + (size_t)ksc * Bq * Dq;
#pragma unroll
      for (int ni = 0; ni < 4; ++ni)
        Pout[(size_t)ty * Dq + n0c + tx * 4 + ni] = acc[ni];
    }
    gsync(p.bar);

    // ---- PD: LSTM epilogue (32 blocks x 1024 threads) ----
    if (blk < 32) {
      int idx = blk * 1024 + tid;
      int b = idx >> 9, e = idx & 511;
      float g0 = p.b_ih[e] + p.b_hh[e];
      float g1 = p.b_ih[Eq + e] + p.b_hh[Eq + e];
      float g2 = p.b_ih[2 * Eq + e] + p.b_hh[2 * Eq + e];
      float g3 = p.b_ih[3 * Eq + e] + p.b_hh[3 * Eq + e];
#pragma unroll
      for (int s = 0; s < 2; ++s) {
        const float* Pr = p.Pwh + ((size_t)s * Bq + b) * Dq;
        g0 += Pr[e]; g1 += Pr[Eq + e]; g2 += Pr[2 * Eq + e]; g3 += Pr[3 * Eq + e];
      }
#pragma unroll
      for (int s = 0; s < 2; ++s) {
        const float* Pr = p.Pge + ((size_t)s * Bq + b) * Dq;
        g0 += Pr[e]; g1 += Pr[Eq + e]; g2 += Pr[2 * Eq + e]; g3 += Pr[3 * Eq + e];
      }
#pragma unroll
      for (int s = 0; s < 8; ++s) {
        const float* Pr = p.Pg + ((size_t)s * Bq + b) * Dq;
        g0 += Pr[e]; g1 += Pr[Eq + e]; g2 += Pr[2 * Eq + e]; g3 += Pr[3 * Eq + e];
      }
      float ig = sigf(g0), fg = sigf(g1), gg = tanhf(g2), og = sigf(g3);
      float cn = fg * p.c[idx] + ig * gg;
      p.c[idx] = cn;
      p.hseq[(size_t)t * Bq * Eq + idx] = og * tanhf(cn);
    }
    gsync(p.bar);
  }
}

// ---------------- final batched preds GEMM (fp32, BM=128 BN=64) ----------------
__global__ __launch_bounds__(256) void gemm_out_big(const float* __restrict__ hseq,
                                                    const float* __restrict__ W_out,
                                                    const float* __restrict__ b_out,
                                                    float* __restrict__ out) {
  __shared__ float As[32][132];
  __shared__ float Ws[32][68];
  const int tid = threadIdx.x;
  const int tx = tid & 15, ty = tid >> 4;
  const int m0 = blockIdx.x * 128, n0 = blockIdx.y * 64;
  float acc[8][4] = {};
  for (int k0 = 0; k0 < Eq; k0 += 32) {
#pragma unroll
    for (int i = 0; i < 4; ++i) {
      int idx = tid + i * 256;
      int r = idx >> 3, c = (idx & 7) << 2;
      const float4 a = *reinterpret_cast<const float4*>(hseq + (size_t)(m0 + r) * Eq + k0 + c);
      As[c + 0][r] = a.x; As[c + 1][r] = a.y; As[c + 2][r] = a.z; As[c + 3][r] = a.w;
    }
#pragma unroll
    for (int i = 0; i < 2; ++i) {
      int idx = tid + i * 256;
      int r = idx >> 3, c = (idx & 7) << 2;
      int wr2 = n0 + r; if (wr2 >= Vq) wr2 = Vq - 1;
      const float4 w = *reinterpret_cast<const float4*>(W_out + (size_t)wr2 * Eq + k0 + c);
      Ws[c + 0][r] = w.x; Ws[c + 1][r] = w.y; Ws[c + 2][r] = w.z; Ws[c + 3][r] = w.w;
    }
    __syncthreads();
#pragma unroll
    for (int k = 0; k < 32; ++k) {
      float a[8], w[4];
#pragma unroll
      for (int i = 0; i < 8; ++i) a[i] = As[k][ty * 8 + i];
#pragma unroll
      for (int j = 0; j < 4; ++j) w[j] = Ws[k][tx * 4 + j];
#pragma unroll
      for (int i = 0; i < 8; ++i)
#pragma unroll
        for (int j = 0; j < 4; ++j) acc[i][j] = fmaf(a[i], w[j], acc[i][j]);
    }
    __syncthreads();
  }
#pragma unroll
  for (int j = 0; j < 4; ++j) {
    int n = n0 + tx * 4 + j;
    if (n < Vq) {
      float bv = b_out[n];
#pragma unroll
      for (int i = 0; i < 8; ++i) {
        int m = m0 + ty * 8 + i;
        int t = m >> 6, b = m & 63;
        out[((size_t)b * Tq + t) * Vq + n] = acc[i][j] + bv;
      }
    }
  }
}

}  // namespace

extern "C" void kernel_launch(void* const* d_in, const int* in_sizes, int n_in,
                              void* d_out, int out_size, void* d_ws, size_t ws_size,
                              hipStream_t stream) {
  (void)in_sizes; (void)n_in; (void)out_size; (void)ws_size;
  const float* img      = (const float*)d_in[0];
  const int*   caps     = (const int*)d_in[1];
  const float* emb      = (const float*)d_in[2];
  const float* W_init_h = (const float*)d_in[3];
  const float* b_init_h = (const float*)d_in[4];
  const float* W_init_c = (const float*)d_in[5];
  const float* b_init_c = (const float*)d_in[6];
  const float* W_fbeta  = (const float*)d_in[7];
  const float* b_fbeta  = (const float*)d_in[8];
  const float* U_att    = (const float*)d_in[9];
  const float* b_Uatt   = (const float*)d_in[10];
  const float* W_att    = (const float*)d_in[11];
  const float* b_Watt   = (const float*)d_in[12];
  const float* v_att    = (const float*)d_in[13];
  const float* b_vatt   = (const float*)d_in[14];
  const float* W_ih     = (const float*)d_in[15];
  const float* b_ih     = (const float*)d_in[16];
  const float* W_hh     = (const float*)d_in[17];
  const float* b_hh     = (const float*)d_in[18];
  const float* W_out    = (const float*)d_in[19];
  const float* b_out    = (const float*)d_in[20];

  float* out = (float*)d_out;
  float* alphas_out = out + (size_t)Bq * Tq * Vq;

  float* ws = (float*)d_ws;
  ushort* img16   = (ushort*)ws; ws += N_IMG / 2;
  ushort* Watt16  = (ushort*)ws; ws += ((size_t)Eq * Dq) / 2;
  ushort* fproj16 = (ushort*)ws; ws += ((size_t)Bq * Pq * Eq) / 2;
  float* hseq  = ws; ws += (size_t)Tq * Bq * Eq;
  float* h0    = ws; ws += Bq * Eq;
  float* c     = ws; ws += Bq * Eq;
  float* ctxg  = ws; ws += Bq * Dq;
  float* ev_g  = ws; ws += Bq * 256;
  float* Pah   = ws; ws += (size_t)2 * Bq * Eq;
  float* Pfb   = ws; ws += (size_t)2 * Bq * Dq;
  float* Pwh   = ws; ws += (size_t)2 * Bq * Dq;
  float* Pge   = ws; ws += (size_t)2 * Bq * Dq;
  float* Pg    = ws; ws += (size_t)8 * Bq * Dq;
  float* avg   = ws; ws += Bq * Dq;
  float* initP = ws; ws += (size_t)16 * Bq * Eq;
  unsigned* bar = (unsigned*)ws; ws += 256;

  // ---- prolog ----
  bar_init<<<1, 256, 0, stream>>>(bar);
  cvt_all<<<(int)((N_IMG / 8 + (size_t)Eq * Dq / 8) / 256), 256, 0, stream>>>(img, W_att, img16,
                                                                              Watt16);
  avg_kernel<<<Bq * Dq / 256, 256, 0, stream>>>(img, avg);
  init_partial<<<dim3(8, 8, 2), 256, 0, stream>>>(avg, W_init_h, W_init_c, initP);
  init_epi<<<2 * Bq * Eq / 256, 256, 0, stream>>>(initP, b_init_h, b_init_c, h0, c);
  fproj_mfma<<<dim3(Bq * Pq / 128, Eq / 64), 256, 0, stream>>>(img16, Watt16, b_Watt, fproj16);

  // ---- 32-step recurrence: persistent kernel, 5 phases/step ----
  StepParams sp;
  sp.caps = caps; sp.emb = emb; sp.U_att = U_att; sp.b_Uatt = b_Uatt;
  sp.W_fbeta = W_fbeta; sp.b_fbeta = b_fbeta; sp.v_att = v_att; sp.b_vatt = b_vatt;
  sp.W_ih = W_ih; sp.b_ih = b_ih; sp.W_hh = W_hh; sp.b_hh = b_hh;
  sp.img16 = img16; sp.fproj16 = fproj16; sp.h0 = h0;
  sp.c = c; sp.hseq = hseq; sp.ctxg = ctxg; sp.ev_g = ev_g;
  sp.Pah = Pah; sp.Pfb = Pfb; sp.Pwh = Pwh; sp.Pge = Pge; sp.Pg = Pg;
  sp.alphas_out = alphas_out; sp.bar = bar;
  step_loop<<<NBLK, 1024, 0, stream>>>(sp);

  // ---- batched preds GEMM ----
  gemm_out_big<<<dim3(Tq * Bq / 128, 157), 256, 0, stream>>>(hseq, W_out, b_out, out);
}

// Round 17
// 4028.412 us; speedup vs baseline: 1.1215x; 1.1141x over previous
//
#include <hip/hip_runtime.h>
#include <math.h>

namespace {

constexpr int Bq = 64, Pq = 196, Dq = 2048, Eq = 512, Vq = 10000, Tq = 32, T1q = 33;
constexpr size_t N_IMG = (size_t)Bq * Pq * Dq;  // 25,690,112
constexpr int NBLK = 256;

typedef __attribute__((ext_vector_type(8))) short bf16x8;
typedef __attribute__((ext_vector_type(4))) float f32x4;

__device__ __forceinline__ float sigf(float x) { return 1.f / (1.f + expf(-x)); }

__device__ __forceinline__ ushort f2bf(float f) {
  union { float f; unsigned u; } v; v.f = f;
  unsigned u = v.u;
  return (ushort)((u + 0x7fffu + ((u >> 16) & 1u)) >> 16);  // RNE
}
__device__ __forceinline__ float bf2f(ushort h) {
  union { unsigned u; float f; } v; v.u = ((unsigned)h) << 16;
  return v.f;
}

// ---- explicitly-coherent accessors (bypass L1/L2; hit the L3 coherence point).
// R8-proven: comm data goes through these; read-only streams stay L2-cached. ----
__device__ __forceinline__ float coh_load(const float* p) {
  union { unsigned u; float f; } c;
  c.u = __hip_atomic_load((const unsigned*)p, __ATOMIC_RELAXED, __HIP_MEMORY_SCOPE_AGENT);
  return c.f;
}
__device__ __forceinline__ float2 coh_load2(const float* p) {
  union { unsigned long long u; float2 f; } c;
  c.u = __hip_atomic_load((const unsigned long long*)p, __ATOMIC_RELAXED,
                          __HIP_MEMORY_SCOPE_AGENT);
  return c.f;
}
__device__ __forceinline__ void coh_store(float* p, float v) {
  union { unsigned u; float f; } c; c.f = v;
  __hip_atomic_store((unsigned*)p, c.u, __ATOMIC_RELAXED, __HIP_MEMORY_SCOPE_AGENT);
}
__device__ __forceinline__ void coh_store2(float* p, float a, float b) {
  union { unsigned long long u; float2 f; } c; c.f = make_float2(a, b);
  __hip_atomic_store((unsigned long long*)p, c.u, __ATOMIC_RELAXED, __HIP_MEMORY_SCOPE_AGENT);
}

// ---- grid barrier (R8-proven semantics: agent release before arrival,
// workgroup acquire after wakeup — NO L2 invalidate; comm is per-access coherent) ----
__device__ __forceinline__ void gsync(unsigned* bar) {
  __syncthreads();
  if (threadIdx.x == 0) {
    __builtin_amdgcn_fence(__ATOMIC_RELEASE, "agent");
    unsigned g = __hip_atomic_load(&bar[144], __ATOMIC_RELAXED, __HIP_MEMORY_SCOPE_AGENT);
    unsigned shard = ((unsigned)blockIdx.x & 7u) * 16u;
    unsigned a = __hip_atomic_fetch_add(&bar[shard], 1u, __ATOMIC_RELAXED,
                                        __HIP_MEMORY_SCOPE_AGENT);
    if (a == 31u) {
      unsigned tot = __hip_atomic_fetch_add(&bar[128], 32u, __ATOMIC_RELAXED,
                                            __HIP_MEMORY_SCOPE_AGENT);
      if (tot == (unsigned)NBLK - 32u) {
        for (unsigned i = 0; i < 8; ++i)
          __hip_atomic_store(&bar[i * 16u], 0u, __ATOMIC_RELAXED, __HIP_MEMORY_SCOPE_AGENT);
        __hip_atomic_store(&bar[128], 0u, __ATOMIC_RELAXED, __HIP_MEMORY_SCOPE_AGENT);
        __hip_atomic_store(&bar[144], g + 1u, __ATOMIC_RELEASE, __HIP_MEMORY_SCOPE_AGENT);
      }
    }
    while (__hip_atomic_load(&bar[144], __ATOMIC_RELAXED, __HIP_MEMORY_SCOPE_AGENT) == g) {
      __builtin_amdgcn_s_sleep(1);
    }
    __builtin_amdgcn_fence(__ATOMIC_ACQUIRE, "workgroup");  // ordering only; keeps L2 warm
  }
  __syncthreads();
}

__global__ void bar_init(unsigned* bar) { bar[threadIdx.x] = 0u; }

// ---------------- prolog kernels (unchanged) ----------------

__global__ __launch_bounds__(256) void cvt_all(const float* __restrict__ img,
                                               const float* __restrict__ Watt,
                                               ushort* __restrict__ img16,
                                               ushort* __restrict__ Watt16) {
  int u = blockIdx.x * 256 + threadIdx.x;
  constexpr int NU_IMG = (int)(N_IMG / 8);
  const float* src; ushort* dst; int off;
  if (u < NU_IMG) { src = img; dst = img16; off = u; }
  else { src = Watt; dst = Watt16; off = u - NU_IMG; }
  const float4 a = reinterpret_cast<const float4*>(src)[2 * (size_t)off];
  const float4 b = reinterpret_cast<const float4*>(src)[2 * (size_t)off + 1];
  union { ushort s[8]; uint4 v; } o;
  o.s[0] = f2bf(a.x); o.s[1] = f2bf(a.y); o.s[2] = f2bf(a.z); o.s[3] = f2bf(a.w);
  o.s[4] = f2bf(b.x); o.s[5] = f2bf(b.y); o.s[6] = f2bf(b.z); o.s[7] = f2bf(b.w);
  reinterpret_cast<uint4*>(dst)[off] = o.v;
}

__global__ __launch_bounds__(256) void avg_kernel(const float* __restrict__ img,
                                                  float* __restrict__ avg) {
  int idx = blockIdx.x * 256 + threadIdx.x;
  int b = idx >> 11, d = idx & (Dq - 1);
  const float* ib = img + (size_t)b * Pq * Dq + d;
  float s = 0.f;
  for (int p = 0; p < Pq; ++p) s += ib[(size_t)p * Dq];
  avg[idx] = s * (1.f / Pq);
}

__global__ __launch_bounds__(256) void init_partial(const float* __restrict__ avg,
                                                    const float* __restrict__ Wh,
                                                    const float* __restrict__ Wc,
                                                    float* __restrict__ P) {
  __shared__ float smem[4224];
  float (*As)[66] = reinterpret_cast<float(*)[66]>(smem);
  float (*Ws)[66] = reinterpret_cast<float(*)[66]>(smem + 32 * 66);
  const float* W = blockIdx.z ? Wc : Wh;
  float* Pout = P + (size_t)blockIdx.z * 8 * Bq * Eq + (size_t)blockIdx.y * Bq * Eq;
  const int tid = threadIdx.x;
  const int tx = tid & 15, ty = tid >> 4;
  const int n0 = blockIdx.x * 64, kbeg = blockIdx.y * 256;
  float acc[4][4] = {};
  for (int it = 0; it < 8; ++it) {
    const int k0 = kbeg + it * 32;
#pragma unroll
    for (int i = 0; i < 2; ++i) {
      int idx = tid + i * 256, r = idx >> 3, c = (idx & 7) << 2;
      const float4 a = *reinterpret_cast<const float4*>(avg + (size_t)r * Dq + k0 + c);
      As[c + 0][r] = a.x; As[c + 1][r] = a.y; As[c + 2][r] = a.z; As[c + 3][r] = a.w;
      const float4 w = *reinterpret_cast<const float4*>(W + (size_t)(n0 + r) * Dq + k0 + c);
      Ws[c + 0][r] = w.x; Ws[c + 1][r] = w.y; Ws[c + 2][r] = w.z; Ws[c + 3][r] = w.w;
    }
    __syncthreads();
#pragma unroll
    for (int k = 0; k < 32; ++k) {
      float av[4], wv[4];
#pragma unroll
      for (int i2 = 0; i2 < 4; ++i2) { av[i2] = As[k][ty * 4 + i2]; wv[i2] = Ws[k][tx * 4 + i2]; }
#pragma unroll
      for (int mi = 0; mi < 4; ++mi)
#pragma unroll
        for (int ni = 0; ni < 4; ++ni) acc[mi][ni] = fmaf(av[mi], wv[ni], acc[mi][ni]);
    }
    __syncthreads();
  }
#pragma unroll
  for (int ni = 0; ni < 4; ++ni)
#pragma unroll
    for (int mi = 0; mi < 4; ++mi)
      Pout[(size_t)(ty * 4 + mi) * Eq + n0 + tx * 4 + ni] = acc[mi][ni];
}

__global__ __launch_bounds__(256) void init_epi(const float* __restrict__ P,
                                                const float* __restrict__ b_h,
                                                const float* __restrict__ b_c,
                                                float* __restrict__ h0,
                                                float* __restrict__ c) {
  int idx = blockIdx.x * 256 + threadIdx.x;
  int which = idx >> 15, j = idx & 32767;
  int b = j >> 9, e = j & 511;
  const float* Pp = P + (size_t)which * 8 * Bq * Eq;
  float s = which ? b_c[e] : b_h[e];
#pragma unroll
  for (int sp = 0; sp < 8; ++sp) s += Pp[((size_t)sp * Bq + b) * Eq + e];
  float v = tanhf(s);
  if (which) c[j] = v; else h0[j] = v;
}

// fproj16 = bf16(img16 @ Watt16^T + b_Watt) via bf16 MFMA. grid (98, 8).
__global__ __launch_bounds__(256) void fproj_mfma(const ushort* __restrict__ A16,
                                                  const ushort* __restrict__ B16,
                                                  const float* __restrict__ bias,
                                                  ushort* __restrict__ C16) {
  __shared__ ushort As[128 * 32];
  __shared__ ushort Bs[64 * 32];
  const int tid = threadIdx.x;
  const int lane = tid & 63, wave = tid >> 6;
  const int m0 = blockIdx.x * 128, n0 = blockIdx.y * 64;
  const int wr = (wave >> 1) * 64, wc = (wave & 1) * 32;
  f32x4 acc[4][2] = {};
  const int ar = tid >> 1, seg = (tid & 1) * 16;
  const int br = (tid & 127) >> 1;
  for (int k0 = 0; k0 < Dq; k0 += 32) {
    const ushort* ga = A16 + (size_t)(m0 + ar) * Dq + k0 + seg;
    uint4 a0 = *reinterpret_cast<const uint4*>(ga);
    uint4 a1 = *reinterpret_cast<const uint4*>(ga + 8);
    unsigned ab = (unsigned)(ar * 64 + seg * 2);
    unsigned sw = (unsigned)((ar & 7) << 4);
    *reinterpret_cast<uint4*>(reinterpret_cast<char*>(As) + (ab ^ sw)) = a0;
    *reinterpret_cast<uint4*>(reinterpret_cast<char*>(As) + ((ab + 16) ^ sw)) = a1;
    if (tid < 128) {
      const ushort* gb = B16 + (size_t)(n0 + br) * Dq + k0 + seg;
      uint4 b0 = *reinterpret_cast<const uint4*>(gb);
      uint4 b1 = *reinterpret_cast<const uint4*>(gb + 8);
      unsigned bb = (unsigned)(br * 64 + seg * 2);
      unsigned sb = (unsigned)((br & 7) << 4);
      *reinterpret_cast<uint4*>(reinterpret_cast<char*>(Bs) + (bb ^ sb)) = b0;
      *reinterpret_cast<uint4*>(reinterpret_cast<char*>(Bs) + ((bb + 16) ^ sb)) = b1;
    }
    __syncthreads();
    const int g = lane >> 4;
    bf16x8 af[4], bfr[2];
#pragma unroll
    for (int i = 0; i < 4; ++i) {
      int row = wr + i * 16 + (lane & 15);
      af[i] = *reinterpret_cast<const bf16x8*>(
          reinterpret_cast<char*>(As) + ((unsigned)(row * 64 + g * 16) ^ ((row & 7) << 4)));
    }
#pragma unroll
    for (int j = 0; j < 2; ++j) {
      int col = wc + j * 16 + (lane & 15);
      bfr[j] = *reinterpret_cast<const bf16x8*>(
          reinterpret_cast<char*>(Bs) + ((unsigned)(col * 64 + g * 16) ^ ((col & 7) << 4)));
    }
#pragma unroll
    for (int i = 0; i < 4; ++i)
#pragma unroll
      for (int j = 0; j < 2; ++j)
        acc[i][j] = __builtin_amdgcn_mfma_f32_16x16x32_bf16(af[i], bfr[j], acc[i][j], 0, 0, 0);
    __syncthreads();
  }
#pragma unroll
  for (int i = 0; i < 4; ++i) {
#pragma unroll
    for (int j = 0; j < 2; ++j) {
      int n = n0 + wc + j * 16 + (lane & 15);
      float bv = bias[n];
#pragma unroll
      for (int q = 0; q < 4; ++q) {
        int m = m0 + wr + i * 16 + (lane >> 4) * 4 + q;
        C16[(size_t)m * Eq + n] = f2bf(acc[i][j][q] + bv);
      }
    }
  }
}

// ---------------- persistent step-loop ----------------

struct StepParams {
  const int* caps;
  const float* emb;
  const float* U_att;
  const float* b_Uatt;
  const float* W_fbeta;
  const float* b_fbeta;
  const float* v_att;
  const float* b_vatt;
  const float* W_ih;
  const float* b_ih;
  const float* W_hh;
  const float* b_hh;
  const ushort* img16;
  const ushort* fproj16;
  const float* h0;
  float* c;
  float* hseq;
  float* ctxg;
  float* ev_g;
  float* Pah;
  float* Pfb;
  float* Pwh;
  float* Pge;
  float* Pg;
  float* alphas_out;
  unsigned* bar;
};

// 64x64 out tile over a K=256 slice; W in LDS bf16; 1024 threads, acc[4].
// MODE 0: A row-major coherent (comm data). MODE 1: emb gather (read-only, cached).
template <int MODE>
__device__ __forceinline__ void gemm_ldsw(
    const float* __restrict__ A, int lda, int kbase,
    const ushort (* __restrict__ Ws)[64],
    const float* __restrict__ emb, const int* __restrict__ caps, int t,
    float (*As)[66], int tid, float acc[4]) {
  const int tx = tid & 15, ty = tid >> 4;
  const int cc = (tid & 15) * 2;
  float2 pa;
  auto loadA = [&](int kc) {
    if (MODE == 1) {
      int tok = caps[ty * T1q + t];
      pa = *reinterpret_cast<const float2*>(emb + (size_t)tok * Eq + kbase + kc * 32 + cc);
    } else {
      pa = coh_load2(A + (size_t)ty * lda + kbase + kc * 32 + cc);
    }
  };
  loadA(0);
  for (int kc = 0; kc < 8; ++kc) {
    As[cc + 0][ty] = pa.x; As[cc + 1][ty] = pa.y;
    __syncthreads();
    if (kc < 7) loadA(kc + 1);
#pragma unroll
    for (int k = 0; k < 32; ++k) {
      float av = As[k][ty];
      uint2 wu = *reinterpret_cast<const uint2*>(&Ws[kc * 32 + k][tx * 4]);
      acc[0] = fmaf(av, bf2f((ushort)(wu.x & 0xffffu)), acc[0]);
      acc[1] = fmaf(av, bf2f((ushort)(wu.x >> 16)), acc[1]);
      acc[2] = fmaf(av, bf2f((ushort)(wu.y & 0xffffu)), acc[2]);
      acc[3] = fmaf(av, bf2f((ushort)(wu.y >> 16)), acc[3]);
    }
    __syncthreads();
  }
}

__global__ __launch_bounds__(1024) void step_loop(StepParams p) {
  __shared__ ushort WsRole[256][64];   // 32 KB
  __shared__ ushort WsCtx[256][64];    // 32 KB
  __shared__ ushort Fs[49 * 512];      // 50 KB: this block's fproj slice
  __shared__ float As[32][66];         // 8.25 KB
  __shared__ float scr[4608];          // 18 KB
  const int blk = blockIdx.x;
  const int tid = threadIdx.x;

  // ---- stage weights + fproj slice to LDS once ----
  {
    const float* Wsrc = nullptr; int n0 = 0, koff = 0, ld = Eq;
    if (blk < 16)       { Wsrc = p.U_att;   n0 = (blk & 7) * 64;  koff = (blk >> 3) * 256; }
    else if (blk < 80)  { int i2 = blk - 16;  Wsrc = p.W_fbeta; n0 = (i2 & 31) * 64; koff = (i2 >> 5) * 256; }
    else if (blk < 144) { int i2 = blk - 80;  Wsrc = p.W_hh;    n0 = (i2 & 31) * 64; koff = (i2 >> 5) * 256; }
    else if (blk < 208) { int i2 = blk - 144; Wsrc = p.W_ih;    n0 = (i2 & 31) * 64; koff = (i2 >> 5) * 256; ld = Eq + Dq; }
    if (Wsrc) {
      for (int i = tid; i < 4096; i += 1024) {
        int r = i >> 6, c4 = (i & 63) << 2;
        const float4 w = *reinterpret_cast<const float4*>(Wsrc + (size_t)(n0 + r) * ld + koff + c4);
        WsRole[c4 + 0][r] = f2bf(w.x); WsRole[c4 + 1][r] = f2bf(w.y);
        WsRole[c4 + 2][r] = f2bf(w.z); WsRole[c4 + 3][r] = f2bf(w.w);
      }
    }
    int n0c = (blk & 31) * 64, kc = (blk >> 5) * 256;
    for (int i = tid; i < 4096; i += 1024) {
      int r = i >> 6, c4 = (i & 63) << 2;
      const float4 w = *reinterpret_cast<const float4*>(
          p.W_ih + (size_t)(n0c + r) * (Eq + Dq) + Eq + kc + c4);
      WsCtx[c4 + 0][r] = f2bf(w.x); WsCtx[c4 + 1][r] = f2bf(w.y);
      WsCtx[c4 + 2][r] = f2bf(w.z); WsCtx[c4 + 3][r] = f2bf(w.w);
    }
    const int fb = blk >> 2, fp0 = (blk & 3) * 49;
    const ushort* src = p.fproj16 + ((size_t)fb * Pq + fp0) * Eq;
    for (int i = tid; i < 49 * 512 / 8; i += 1024) {
      reinterpret_cast<uint4*>(Fs)[i] = reinterpret_cast<const uint4*>(src)[i];
    }
    __syncthreads();
  }

  const int tx = tid & 15, ty = tid >> 4;
  const int n0c = (blk & 31) * 64, ksc = blk >> 5;

  for (int t = 0; t < Tq; ++t) {
    const float* hc = (t == 0) ? p.h0 : p.hseq + (size_t)(t - 1) * Bq * Eq;

    // ---- PA: att_h | fbeta | Whh | emb-gates (LDS-W GEMM partials; coherent A/P) ----
    if (blk < 208) {
      float acc[4] = {};
      float* Pout; int n0, Npad;
      if (blk < 16) {
        int ks = blk >> 3; n0 = (blk & 7) * 64; Npad = Eq;
        gemm_ldsw<0>(hc, Eq, ks * 256, WsRole, nullptr, nullptr, t, As, tid, acc);
        Pout = p.Pah + (size_t)ks * Bq * Eq;
      } else if (blk < 80) {
        int i2 = blk - 16, ks = i2 >> 5; n0 = (i2 & 31) * 64; Npad = Dq;
        gemm_ldsw<0>(hc, Eq, ks * 256, WsRole, nullptr, nullptr, t, As, tid, acc);
        Pout = p.Pfb + (size_t)ks * Bq * Dq;
      } else if (blk < 144) {
        int i2 = blk - 80, ks = i2 >> 5; n0 = (i2 & 31) * 64; Npad = Dq;
        gemm_ldsw<0>(hc, Eq, ks * 256, WsRole, nullptr, nullptr, t, As, tid, acc);
        Pout = p.Pwh + (size_t)ks * Bq * Dq;
      } else {
        int i2 = blk - 144, ks = i2 >> 5; n0 = (i2 & 31) * 64; Npad = Dq;
        gemm_ldsw<1>(nullptr, 0, ks * 256, WsRole, p.emb, p.caps, t, As, tid, acc);
        Pout = p.Pge + (size_t)ks * Bq * Dq;
      }
      float* dst = Pout + (size_t)ty * Npad + n0 + tx * 4;
      coh_store2(dst, acc[0], acc[1]);
      coh_store2(dst + 2, acc[2], acc[3]);
    }
    gsync(p.bar);

    // ---- PB1: e-scores from LDS fproj slice ----
    {
      const int b = blk >> 2, pq = blk & 3;
      const int lane = tid & 63, wv = tid >> 6;
      float* ah = scr; float* vs = scr + 512;
      if (tid < Eq) {
        ah[tid] = p.b_Uatt[tid] + coh_load(&p.Pah[(size_t)b * Eq + tid])
                + coh_load(&p.Pah[(size_t)Bq * Eq + b * Eq + tid]);
        vs[tid] = p.v_att[tid];
      }
      __syncthreads();
      const float bv = p.b_vatt[0];
      const int pbeg = pq * 49;
      const int k8 = lane * 8;
      for (int pl = wv; pl < 49; pl += 16) {
        const ushort* f0 = Fs + pl * Eq + k8;
        uint4 va = *reinterpret_cast<const uint4*>(f0);
        float s = 0.f;
        const unsigned u[4] = {va.x, va.y, va.z, va.w};
#pragma unroll
        for (int j = 0; j < 4; ++j) {
          s = fmaf(tanhf(bf2f((ushort)(u[j] & 0xffffu)) + ah[k8 + j * 2]), vs[k8 + j * 2], s);
          s = fmaf(tanhf(bf2f((ushort)(u[j] >> 16)) + ah[k8 + j * 2 + 1]), vs[k8 + j * 2 + 1], s);
        }
#pragma unroll
        for (int off = 32; off > 0; off >>= 1) s += __shfl_xor(s, off);
        if (lane == 0) coh_store(&p.ev_g[b * 256 + pbeg + pl], s + bv);
      }
      __syncthreads();
    }
    gsync(p.bar);

    // ---- PB2: softmax (redundant x4) + gated context 512-d slice ----
    {
      const int b = blk >> 2, sl = blk & 3;
      float* pc = scr;            // 4096
      float* al = scr + 4096;     // 196
      float* red = scr + 4352;    // 256
      float x = (tid < Pq) ? coh_load(&p.ev_g[b * 256 + tid]) : -INFINITY;
      if (tid < 256) red[tid] = x;
      __syncthreads();
      for (int s2 = 128; s2 > 0; s2 >>= 1) {
        if (tid < s2) red[tid] = fmaxf(red[tid], red[tid + s2]);
        __syncthreads();
      }
      float mx = red[0];
      __syncthreads();
      float ex = (tid < Pq) ? expf(x - mx) : 0.f;
      if (tid < 256) red[tid] = ex;
      __syncthreads();
      for (int s2 = 128; s2 > 0; s2 >>= 1) {
        if (tid < s2) red[tid] += red[tid + s2];
        __syncthreads();
      }
      float inv = 1.f / red[0];
      if (tid < Pq) {
        float a = ex * inv;
        al[tid] = a;
        if (sl == 0) p.alphas_out[((size_t)b * Tq + t) * Pq + tid] = a;
      }
      __syncthreads();
      const int tid2 = tid & 127, ph = tid >> 7;
      const int d4 = tid2 * 4, d = sl * 512 + d4;
      const int pb2 = (ph * 196) >> 3, pe2 = ((ph + 1) * 196) >> 3;
      const ushort* ib = p.img16 + (size_t)b * Pq * Dq + d;   // NORMAL load: L2-resident
      float s0 = 0.f, s1 = 0.f, s2a = 0.f, s3 = 0.f;
      for (int pp = pb2; pp < pe2; ++pp) {
        uint2 v = *reinterpret_cast<const uint2*>(ib + (size_t)pp * Dq);
        float a = al[pp];
        s0 = fmaf(a, bf2f((ushort)(v.x & 0xffffu)), s0);
        s1 = fmaf(a, bf2f((ushort)(v.x >> 16)), s1);
        s2a = fmaf(a, bf2f((ushort)(v.y & 0xffffu)), s2a);
        s3 = fmaf(a, bf2f((ushort)(v.y >> 16)), s3);
      }
      pc[ph * 512 + d4 + 0] = s0; pc[ph * 512 + d4 + 1] = s1;
      pc[ph * 512 + d4 + 2] = s2a; pc[ph * 512 + d4 + 3] = s3;
      __syncthreads();
      if (tid < 512) {
        float sum = 0.f;
#pragma unroll
        for (int q = 0; q < 8; ++q) sum += pc[q * 512 + tid];
        int dd = sl * 512 + tid;
        float g = sigf(p.b_fbeta[dd] + coh_load(&p.Pfb[(size_t)b * Dq + dd])
                       + coh_load(&p.Pfb[(size_t)Bq * Dq + b * Dq + dd]));
        coh_store(&p.ctxg[(size_t)b * Dq + dd], sum * g);
      }
      __syncthreads();
    }
    gsync(p.bar);

    // ---- PC: ctx-gates GEMM partials (all 256 blocks, LDS-W; coherent A/P) ----
    {
      float acc[4] = {};
      gemm_ldsw<0>(p.ctxg, Dq, ksc * 256, WsCtx, nullptr, nullptr, t, As, tid, acc);
      float* dst = p.Pg + (size_t)ksc * Bq * Dq + (size_t)ty * Dq + n0c + tx * 4;
      coh_store2(dst, acc[0], acc[1]);
      coh_store2(dst + 2, acc[2], acc[3]);
    }
    gsync(p.bar);

    // ---- PD: LSTM epilogue (32 blocks x 1024 threads; coherent partial reads) ----
    if (blk < 32) {
      int idx = blk * 1024 + tid;
      int b = idx >> 9, e = idx & 511;
      float g0 = p.b_ih[e] + p.b_hh[e];
      float g1 = p.b_ih[Eq + e] + p.b_hh[Eq + e];
      float g2 = p.b_ih[2 * Eq + e] + p.b_hh[2 * Eq + e];
      float g3 = p.b_ih[3 * Eq + e] + p.b_hh[3 * Eq + e];
#pragma unroll
      for (int s = 0; s < 2; ++s) {
        const float* Pr = p.Pwh + ((size_t)s * Bq + b) * Dq;
        g0 += coh_load(Pr + e); g1 += coh_load(Pr + Eq + e);
        g2 += coh_load(Pr + 2 * Eq + e); g3 += coh_load(Pr + 3 * Eq + e);
      }
#pragma unroll
      for (int s = 0; s < 2; ++s) {
        const float* Pr = p.Pge + ((size_t)s * Bq + b) * Dq;
        g0 += coh_load(Pr + e); g1 += coh_load(Pr + Eq + e);
        g2 += coh_load(Pr + 2 * Eq + e); g3 += coh_load(Pr + 3 * Eq + e);
      }
#pragma unroll
      for (int s = 0; s < 8; ++s) {
        const float* Pr = p.Pg + ((size_t)s * Bq + b) * Dq;
        g0 += coh_load(Pr + e); g1 += coh_load(Pr + Eq + e);
        g2 += coh_load(Pr + 2 * Eq + e); g3 += coh_load(Pr + 3 * Eq + e);
      }
      float ig = sigf(g0), fg = sigf(g1), gg = tanhf(g2), og = sigf(g3);
      float cn = fg * p.c[idx] + ig * gg;   // c block-private: normal
      p.c[idx] = cn;
      coh_store(&p.hseq[(size_t)t * Bq * Eq + idx], og * tanhf(cn));
    }
    gsync(p.bar);
  }
}

// ---------------- final batched preds GEMM (fp32, BM=128 BN=64) ----------------
__global__ __launch_bounds__(256) void gemm_out_big(const float* __restrict__ hseq,
                                                    const float* __restrict__ W_out,
                                                    const float* __restrict__ b_out,
                                                    float* __restrict__ out) {
  __shared__ float As[32][132];
  __shared__ float Ws[32][68];
  const int tid = threadIdx.x;
  const int tx = tid & 15, ty = tid >> 4;
  const int m0 = blockIdx.x * 128, n0 = blockIdx.y * 64;
  float acc[8][4] = {};
  for (int k0 = 0; k0 < Eq; k0 += 32) {
#pragma unroll
    for (int i = 0; i < 4; ++i) {
      int idx = tid + i * 256;
      int r = idx >> 3, c = (idx & 7) << 2;
      const float4 a = *reinterpret_cast<const float4*>(hseq + (size_t)(m0 + r) * Eq + k0 + c);
      As[c + 0][r] = a.x; As[c + 1][r] = a.y; As[c + 2][r] = a.z; As[c + 3][r] = a.w;
    }
#pragma unroll
    for (int i = 0; i < 2; ++i) {
      int idx = tid + i * 256;
      int r = idx >> 3, c = (idx & 7) << 2;
      int wr2 = n0 + r; if (wr2 >= Vq) wr2 = Vq - 1;
      const float4 w = *reinterpret_cast<const float4*>(W_out + (size_t)wr2 * Eq + k0 + c);
      Ws[c + 0][r] = w.x; Ws[c + 1][r] = w.y; Ws[c + 2][r] = w.z; Ws[c + 3][r] = w.w;
    }
    __syncthreads();
#pragma unroll
    for (int k = 0; k < 32; ++k) {
      float a[8], w[4];
#pragma unroll
      for (int i = 0; i < 8; ++i) a[i] = As[k][ty * 8 + i];
#pragma unroll
      for (int j = 0; j < 4; ++j) w[j] = Ws[k][tx * 4 + j];
#pragma unroll
      for (int i = 0; i < 8; ++i)
#pragma unroll
        for (int j = 0; j < 4; ++j) acc[i][j] = fmaf(a[i], w[j], acc[i][j]);
    }
    __syncthreads();
  }
#pragma unroll
  for (int j = 0; j < 4; ++j) {
    int n = n0 + tx * 4 + j;
    if (n < Vq) {
      float bv = b_out[n];
#pragma unroll
      for (int i = 0; i < 8; ++i) {
        int m = m0 + ty * 8 + i;
        int t = m >> 6, b = m & 63;
        out[((size_t)b * Tq + t) * Vq + n] = acc[i][j] + bv;
      }
    }
  }
}

}  // namespace

extern "C" void kernel_launch(void* const* d_in, const int* in_sizes, int n_in,
                              void* d_out, int out_size, void* d_ws, size_t ws_size,
                              hipStream_t stream) {
  (void)in_sizes; (void)n_in; (void)out_size; (void)ws_size;
  const float* img      = (const float*)d_in[0];
  const int*   caps     = (const int*)d_in[1];
  const float* emb      = (const float*)d_in[2];
  const float* W_init_h = (const float*)d_in[3];
  const float* b_init_h = (const float*)d_in[4];
  const float* W_init_c = (const float*)d_in[5];
  const float* b_init_c = (const float*)d_in[6];
  const float* W_fbeta  = (const float*)d_in[7];
  const float* b_fbeta  = (const float*)d_in[8];
  const float* U_att    = (const float*)d_in[9];
  const float* b_Uatt   = (const float*)d_in[10];
  const float* W_att    = (const float*)d_in[11];
  const float* b_Watt   = (const float*)d_in[12];
  const float* v_att    = (const float*)d_in[13];
  const float* b_vatt   = (const float*)d_in[14];
  const float* W_ih     = (const float*)d_in[15];
  const float* b_ih     = (const float*)d_in[16];
  const float* W_hh     = (const float*)d_in[17];
  const float* b_hh     = (const float*)d_in[18];
  const float* W_out    = (const float*)d_in[19];
  const float* b_out    = (const float*)d_in[20];

  float* out = (float*)d_out;
  float* alphas_out = out + (size_t)Bq * Tq * Vq;

  float* ws = (float*)d_ws;
  ushort* img16   = (ushort*)ws; ws += N_IMG / 2;
  ushort* Watt16  = (ushort*)ws; ws += ((size_t)Eq * Dq) / 2;
  ushort* fproj16 = (ushort*)ws; ws += ((size_t)Bq * Pq * Eq) / 2;
  float* hseq  = ws; ws += (size_t)Tq * Bq * Eq;
  float* h0    = ws; ws += Bq * Eq;
  float* c     = ws; ws += Bq * Eq;
  float* ctxg  = ws; ws += Bq * Dq;
  float* ev_g  = ws; ws += Bq * 256;
  float* Pah   = ws; ws += (size_t)2 * Bq * Eq;
  float* Pfb   = ws; ws += (size_t)2 * Bq * Dq;
  float* Pwh   = ws; ws += (size_t)2 * Bq * Dq;
  float* Pge   = ws; ws += (size_t)2 * Bq * Dq;
  float* Pg    = ws; ws += (size_t)8 * Bq * Dq;
  float* avg   = ws; ws += Bq * Dq;
  float* initP = ws; ws += (size_t)16 * Bq * Eq;
  unsigned* bar = (unsigned*)ws; ws += 256;

  // ---- prolog ----
  bar_init<<<1, 256, 0, stream>>>(bar);
  cvt_all<<<(int)((N_IMG / 8 + (size_t)Eq * Dq / 8) / 256), 256, 0, stream>>>(img, W_att, img16,
                                                                              Watt16);
  avg_kernel<<<Bq * Dq / 256, 256, 0, stream>>>(img, avg);
  init_partial<<<dim3(8, 8, 2), 256, 0, stream>>>(avg, W_init_h, W_init_c, initP);
  init_epi<<<2 * Bq * Eq / 256, 256, 0, stream>>>(initP, b_init_h, b_init_c, h0, c);
  fproj_mfma<<<dim3(Bq * Pq / 128, Eq / 64), 256, 0, stream>>>(img16, Watt16, b_Watt, fproj16);

  // ---- 32-step recurrence: persistent kernel, 5 phases/step, L2-preserving barrier ----
  StepParams sp;
  sp.caps = caps; sp.emb = emb; sp.U_att = U_att; sp.b_Uatt = b_Uatt;
  sp.W_fbeta = W_fbeta; sp.b_fbeta = b_fbeta; sp.v_att = v_att; sp.b_vatt = b_vatt;
  sp.W_ih = W_ih; sp.b_ih = b_ih; sp.W_hh = W_hh; sp.b_hh = b_hh;
  sp.img16 = img16; sp.fproj16 = fproj16; sp.h0 = h0;
  sp.c = c; sp.hseq = hseq; sp.ctxg = ctxg; sp.ev_g = ev_g;
  sp.Pah = Pah; sp.Pfb = Pfb; sp.Pwh = Pwh; sp.Pge = Pge; sp.Pg = Pg;
  sp.alphas_out = alphas_out; sp.bar = bar;
  step_loop<<<NBLK, 1024, 0, stream>>>(sp);

  // ---- batched preds GEMM ----
  gemm_out_big<<<dim3(Tq * Bq / 128, 157), 256, 0, stream>>>(hseq, W_out, b_out, out);
}

// Round 18
// 4009.149 us; speedup vs baseline: 1.1269x; 1.0048x over previous
//
#include <hip/hip_runtime.h>
#include <math.h>

namespace {

constexpr int Bq = 64, Pq = 196, Dq = 2048, Eq = 512, Vq = 10000, Tq = 32, T1q = 33;
constexpr size_t N_IMG = (size_t)Bq * Pq * Dq;  // 25,690,112
constexpr int NBLK = 256;

typedef __attribute__((ext_vector_type(8))) short bf16x8;
typedef __attribute__((ext_vector_type(4))) float f32x4;

__device__ __forceinline__ float sigf(float x) { return 1.f / (1.f + expf(-x)); }

__device__ __forceinline__ ushort f2bf(float f) {
  union { float f; unsigned u; } v; v.f = f;
  unsigned u = v.u;
  return (ushort)((u + 0x7fffu + ((u >> 16) & 1u)) >> 16);  // RNE
}
__device__ __forceinline__ float bf2f(ushort h) {
  union { unsigned u; float f; } v; v.u = ((unsigned)h) << 16;
  return v.f;
}

// ---- explicitly-coherent accessors (R8/R17-proven) ----
__device__ __forceinline__ float coh_load(const float* p) {
  union { unsigned u; float f; } c;
  c.u = __hip_atomic_load((const unsigned*)p, __ATOMIC_RELAXED, __HIP_MEMORY_SCOPE_AGENT);
  return c.f;
}
__device__ __forceinline__ float2 coh_load2(const float* p) {
  union { unsigned long long u; float2 f; } c;
  c.u = __hip_atomic_load((const unsigned long long*)p, __ATOMIC_RELAXED,
                          __HIP_MEMORY_SCOPE_AGENT);
  return c.f;
}
__device__ __forceinline__ void coh_store(float* p, float v) {
  union { unsigned u; float f; } c; c.f = v;
  __hip_atomic_store((unsigned*)p, c.u, __ATOMIC_RELAXED, __HIP_MEMORY_SCOPE_AGENT);
}
__device__ __forceinline__ void coh_store2(float* p, float a, float b) {
  union { unsigned long long u; float2 f; } c; c.f = make_float2(a, b);
  __hip_atomic_store((unsigned long long*)p, c.u, __ATOMIC_RELAXED, __HIP_MEMORY_SCOPE_AGENT);
}

// ---- grid barrier (R17-proven: agent release, workgroup acquire — keeps L2 warm) ----
__device__ __forceinline__ void gsync(unsigned* bar) {
  __syncthreads();
  if (threadIdx.x == 0) {
    __builtin_amdgcn_fence(__ATOMIC_RELEASE, "agent");
    unsigned g = __hip_atomic_load(&bar[144], __ATOMIC_RELAXED, __HIP_MEMORY_SCOPE_AGENT);
    unsigned shard = ((unsigned)blockIdx.x & 7u) * 16u;
    unsigned a = __hip_atomic_fetch_add(&bar[shard], 1u, __ATOMIC_RELAXED,
                                        __HIP_MEMORY_SCOPE_AGENT);
    if (a == 31u) {
      unsigned tot = __hip_atomic_fetch_add(&bar[128], 32u, __ATOMIC_RELAXED,
                                            __HIP_MEMORY_SCOPE_AGENT);
      if (tot == (unsigned)NBLK - 32u) {
        for (unsigned i = 0; i < 8; ++i)
          __hip_atomic_store(&bar[i * 16u], 0u, __ATOMIC_RELAXED, __HIP_MEMORY_SCOPE_AGENT);
        __hip_atomic_store(&bar[128], 0u, __ATOMIC_RELAXED, __HIP_MEMORY_SCOPE_AGENT);
        __hip_atomic_store(&bar[144], g + 1u, __ATOMIC_RELEASE, __HIP_MEMORY_SCOPE_AGENT);
      }
    }
    while (__hip_atomic_load(&bar[144], __ATOMIC_RELAXED, __HIP_MEMORY_SCOPE_AGENT) == g) {
      __builtin_amdgcn_s_sleep(1);
    }
    __builtin_amdgcn_fence(__ATOMIC_ACQUIRE, "workgroup");
  }
  __syncthreads();
}

__global__ void bar_init(unsigned* bar) { bar[threadIdx.x] = 0u; }

// ---------------- prolog kernels ----------------

// img -> img16p permuted [b][slice(4)][p][512]; Watt -> Watt16 (row-major).
__global__ __launch_bounds__(256) void cvt_all(const float* __restrict__ img,
                                               const float* __restrict__ Watt,
                                               ushort* __restrict__ img16p,
                                               ushort* __restrict__ Watt16) {
  int u = blockIdx.x * 256 + threadIdx.x;
  constexpr int NU_IMG = (int)(N_IMG / 8);
  if (u < NU_IMG) {
    size_t off = (size_t)u * 8;
    int b = (int)(off / ((size_t)Pq * Dq));
    int rem = (int)(off - (size_t)b * Pq * Dq);
    int pp = rem / Dq, d = rem - pp * Dq;
    int sl = d >> 9, dd = d & 511;
    const float4 a = *reinterpret_cast<const float4*>(img + off);
    const float4 bvv = *reinterpret_cast<const float4*>(img + off + 4);
    union { ushort s[8]; uint4 v; } o;
    o.s[0] = f2bf(a.x); o.s[1] = f2bf(a.y); o.s[2] = f2bf(a.z); o.s[3] = f2bf(a.w);
    o.s[4] = f2bf(bvv.x); o.s[5] = f2bf(bvv.y); o.s[6] = f2bf(bvv.z); o.s[7] = f2bf(bvv.w);
    size_t dst = (((size_t)(b * 4 + sl) * Pq) + pp) * 512 + dd;
    *reinterpret_cast<uint4*>(img16p + dst) = o.v;
  } else {
    int off = u - NU_IMG;
    const float4 a = reinterpret_cast<const float4*>(Watt)[2 * (size_t)off];
    const float4 bvv = reinterpret_cast<const float4*>(Watt)[2 * (size_t)off + 1];
    union { ushort s[8]; uint4 v; } o;
    o.s[0] = f2bf(a.x); o.s[1] = f2bf(a.y); o.s[2] = f2bf(a.z); o.s[3] = f2bf(a.w);
    o.s[4] = f2bf(bvv.x); o.s[5] = f2bf(bvv.y); o.s[6] = f2bf(bvv.z); o.s[7] = f2bf(bvv.w);
    reinterpret_cast<uint4*>(Watt16)[off] = o.v;
  }
}

__global__ __launch_bounds__(256) void avg_kernel(const float* __restrict__ img,
                                                  float* __restrict__ avg) {
  int idx = blockIdx.x * 256 + threadIdx.x;
  int b = idx >> 11, d = idx & (Dq - 1);
  const float* ib = img + (size_t)b * Pq * Dq + d;
  float s = 0.f;
  for (int p = 0; p < Pq; ++p) s += ib[(size_t)p * Dq];
  avg[idx] = s * (1.f / Pq);
}

__global__ __launch_bounds__(256) void init_partial(const float* __restrict__ avg,
                                                    const float* __restrict__ Wh,
                                                    const float* __restrict__ Wc,
                                                    float* __restrict__ P) {
  __shared__ float smem[4224];
  float (*As)[66] = reinterpret_cast<float(*)[66]>(smem);
  float (*Ws)[66] = reinterpret_cast<float(*)[66]>(smem + 32 * 66);
  const float* W = blockIdx.z ? Wc : Wh;
  float* Pout = P + (size_t)blockIdx.z * 8 * Bq * Eq + (size_t)blockIdx.y * Bq * Eq;
  const int tid = threadIdx.x;
  const int tx = tid & 15, ty = tid >> 4;
  const int n0 = blockIdx.x * 64, kbeg = blockIdx.y * 256;
  float acc[4][4] = {};
  for (int it = 0; it < 8; ++it) {
    const int k0 = kbeg + it * 32;
#pragma unroll
    for (int i = 0; i < 2; ++i) {
      int idx = tid + i * 256, r = idx >> 3, c = (idx & 7) << 2;
      const float4 a = *reinterpret_cast<const float4*>(avg + (size_t)r * Dq + k0 + c);
      As[c + 0][r] = a.x; As[c + 1][r] = a.y; As[c + 2][r] = a.z; As[c + 3][r] = a.w;
      const float4 w = *reinterpret_cast<const float4*>(W + (size_t)(n0 + r) * Dq + k0 + c);
      Ws[c + 0][r] = w.x; Ws[c + 1][r] = w.y; Ws[c + 2][r] = w.z; Ws[c + 3][r] = w.w;
    }
    __syncthreads();
#pragma unroll
    for (int k = 0; k < 32; ++k) {
      float av[4], wv[4];
#pragma unroll
      for (int i2 = 0; i2 < 4; ++i2) { av[i2] = As[k][ty * 4 + i2]; wv[i2] = Ws[k][tx * 4 + i2]; }
#pragma unroll
      for (int mi = 0; mi < 4; ++mi)
#pragma unroll
        for (int ni = 0; ni < 4; ++ni) acc[mi][ni] = fmaf(av[mi], wv[ni], acc[mi][ni]);
    }
    __syncthreads();
  }
#pragma unroll
  for (int ni = 0; ni < 4; ++ni)
#pragma unroll
    for (int mi = 0; mi < 4; ++mi)
      Pout[(size_t)(ty * 4 + mi) * Eq + n0 + tx * 4 + ni] = acc[mi][ni];
}

__global__ __launch_bounds__(256) void init_epi(const float* __restrict__ P,
                                                const float* __restrict__ b_h,
                                                const float* __restrict__ b_c,
                                                float* __restrict__ h0,
                                                float* __restrict__ c) {
  int idx = blockIdx.x * 256 + threadIdx.x;
  int which = idx >> 15, j = idx & 32767;
  int b = j >> 9, e = j & 511;
  const float* Pp = P + (size_t)which * 8 * Bq * Eq;
  float s = which ? b_c[e] : b_h[e];
#pragma unroll
  for (int sp = 0; sp < 8; ++sp) s += Pp[((size_t)sp * Bq + b) * Eq + e];
  float v = tanhf(s);
  if (which) c[j] = v; else h0[j] = v;
}

// fproj16 from permuted img16p: A row (m = b*196+p) gathers 4 slices.
// BM=128 BN=64 BK=32. grid (98, 8).
__global__ __launch_bounds__(256) void fproj_mfma(const ushort* __restrict__ A16p,
                                                  const ushort* __restrict__ B16,
                                                  const float* __restrict__ bias,
                                                  ushort* __restrict__ C16) {
  __shared__ ushort As[128 * 32];
  __shared__ ushort Bs[64 * 32];
  const int tid = threadIdx.x;
  const int lane = tid & 63, wave = tid >> 6;
  const int m0 = blockIdx.x * 128, n0 = blockIdx.y * 64;
  const int wr = (wave >> 1) * 64, wc = (wave & 1) * 32;
  f32x4 acc[4][2] = {};
  const int ar = tid >> 1, seg = (tid & 1) * 16;
  const int br = (tid & 127) >> 1;
  for (int k0 = 0; k0 < Dq; k0 += 32) {
    // A row m = m0+ar -> (b, p); element k0+seg.. within slice (k>>9), offset k&511
    int m = m0 + ar;
    int b = m / Pq, pp = m - b * Pq;
    int k = k0 + seg;
    int sl = k >> 9, dd = k & 511;
    const ushort* ga = A16p + (((size_t)(b * 4 + sl) * Pq) + pp) * 512 + dd;
    uint4 a0 = *reinterpret_cast<const uint4*>(ga);
    uint4 a1 = *reinterpret_cast<const uint4*>(ga + 8);
    unsigned ab = (unsigned)(ar * 64 + seg * 2);
    unsigned sw = (unsigned)((ar & 7) << 4);
    *reinterpret_cast<uint4*>(reinterpret_cast<char*>(As) + (ab ^ sw)) = a0;
    *reinterpret_cast<uint4*>(reinterpret_cast<char*>(As) + ((ab + 16) ^ sw)) = a1;
    if (tid < 128) {
      const ushort* gb = B16 + (size_t)(n0 + br) * Dq + k0 + seg;
      uint4 b0 = *reinterpret_cast<const uint4*>(gb);
      uint4 b1 = *reinterpret_cast<const uint4*>(gb + 8);
      unsigned bb = (unsigned)(br * 64 + seg * 2);
      unsigned sb = (unsigned)((br & 7) << 4);
      *reinterpret_cast<uint4*>(reinterpret_cast<char*>(Bs) + (bb ^ sb)) = b0;
      *reinterpret_cast<uint4*>(reinterpret_cast<char*>(Bs) + ((bb + 16) ^ sb)) = b1;
    }
    __syncthreads();
    const int g = lane >> 4;
    bf16x8 af[4], bfr[2];
#pragma unroll
    for (int i = 0; i < 4; ++i) {
      int row = wr + i * 16 + (lane & 15);
      af[i] = *reinterpret_cast<const bf16x8*>(
          reinterpret_cast<char*>(As) + ((unsigned)(row * 64 + g * 16) ^ ((row & 7) << 4)));
    }
#pragma unroll
    for (int j = 0; j < 2; ++j) {
      int col = wc + j * 16 + (lane & 15);
      bfr[j] = *reinterpret_cast<const bf16x8*>(
          reinterpret_cast<char*>(Bs) + ((unsigned)(col * 64 + g * 16) ^ ((col & 7) << 4)));
    }
#pragma unroll
    for (int i = 0; i < 4; ++i)
#pragma unroll
      for (int j = 0; j < 2; ++j)
        acc[i][j] = __builtin_amdgcn_mfma_f32_16x16x32_bf16(af[i], bfr[j], acc[i][j], 0, 0, 0);
    __syncthreads();
  }
#pragma unroll
  for (int i = 0; i < 4; ++i) {
#pragma unroll
    for (int j = 0; j < 2; ++j) {
      int n = n0 + wc + j * 16 + (lane & 15);
      float bv = bias[n];
#pragma unroll
      for (int q = 0; q < 4; ++q) {
        int m = m0 + wr + i * 16 + (lane >> 4) * 4 + q;
        C16[(size_t)m * Eq + n] = f2bf(acc[i][j][q] + bv);
      }
    }
  }
}

// ---------------- persistent step-loop ----------------

struct StepParams {
  const int* caps;
  const float* emb;
  const float* U_att;
  const float* b_Uatt;
  const float* W_fbeta;
  const float* b_fbeta;
  const float* v_att;
  const float* b_vatt;
  const float* W_ih;
  const float* b_ih;
  const float* W_hh;
  const float* b_hh;
  const ushort* img16p;
  const ushort* fproj16;
  const float* h0;
  float* c;
  float* hseq;
  float* ctxg;
  float* ev_g;
  float* Pah;
  float* Pfb;
  float* Pwh;
  float* Pge;
  float* Pg;
  float* alphas_out;
  unsigned* bar;
};

// 64x64 out tile over a K=256 slice; W in LDS bf16; 1024 threads, acc[4].
template <int MODE>
__device__ __forceinline__ void gemm_ldsw(
    const float* __restrict__ A, int lda, int kbase,
    const ushort (* __restrict__ Ws)[64],
    const float* __restrict__ emb, const int* __restrict__ caps, int t,
    float (*As)[66], int tid, float acc[4]) {
  const int tx = tid & 15, ty = tid >> 4;
  const int cc = (tid & 15) * 2;
  float2 pa;
  auto loadA = [&](int kc) {
    if (MODE == 1) {
      int tok = caps[ty * T1q + t];
      pa = *reinterpret_cast<const float2*>(emb + (size_t)tok * Eq + kbase + kc * 32 + cc);
    } else {
      pa = coh_load2(A + (size_t)ty * lda + kbase + kc * 32 + cc);
    }
  };
  loadA(0);
  for (int kc = 0; kc < 8; ++kc) {
    As[cc + 0][ty] = pa.x; As[cc + 1][ty] = pa.y;
    __syncthreads();
    if (kc < 7) loadA(kc + 1);
#pragma unroll
    for (int k = 0; k < 32; ++k) {
      float av = As[k][ty];
      uint2 wu = *reinterpret_cast<const uint2*>(&Ws[kc * 32 + k][tx * 4]);
      acc[0] = fmaf(av, bf2f((ushort)(wu.x & 0xffffu)), acc[0]);
      acc[1] = fmaf(av, bf2f((ushort)(wu.x >> 16)), acc[1]);
      acc[2] = fmaf(av, bf2f((ushort)(wu.y & 0xffffu)), acc[2]);
      acc[3] = fmaf(av, bf2f((ushort)(wu.y >> 16)), acc[3]);
    }
    __syncthreads();
  }
}

__global__ __launch_bounds__(1024) void step_loop(StepParams p) {
  __shared__ ushort WsRole[256][64];   // 32 KB
  __shared__ ushort WsCtx[256][64];    // 32 KB
  __shared__ ushort Fs[49 * 512];      // 50 KB: fproj slice
  __shared__ float As[32][66];         // 8.25 KB
  __shared__ float scr[4608];          // 18 KB
  const int blk = blockIdx.x;
  const int tid = threadIdx.x;

  // ---- stage weights + fproj slice to LDS once ----
  {
    const float* Wsrc = nullptr; int n0 = 0, koff = 0, ld = Eq;
    if (blk < 16)       { Wsrc = p.U_att;   n0 = (blk & 7) * 64;  koff = (blk >> 3) * 256; }
    else if (blk < 80)  { int i2 = blk - 16;  Wsrc = p.W_fbeta; n0 = (i2 & 31) * 64; koff = (i2 >> 5) * 256; }
    else if (blk < 144) { int i2 = blk - 80;  Wsrc = p.W_hh;    n0 = (i2 & 31) * 64; koff = (i2 >> 5) * 256; }
    else if (blk < 208) { int i2 = blk - 144; Wsrc = p.W_ih;    n0 = (i2 & 31) * 64; koff = (i2 >> 5) * 256; ld = Eq + Dq; }
    if (Wsrc) {
      for (int i = tid; i < 4096; i += 1024) {
        int r = i >> 6, c4 = (i & 63) << 2;
        const float4 w = *reinterpret_cast<const float4*>(Wsrc + (size_t)(n0 + r) * ld + koff + c4);
        WsRole[c4 + 0][r] = f2bf(w.x); WsRole[c4 + 1][r] = f2bf(w.y);
        WsRole[c4 + 2][r] = f2bf(w.z); WsRole[c4 + 3][r] = f2bf(w.w);
      }
    }
    int n0c = (blk & 31) * 64, kc = (blk >> 5) * 256;
    for (int i = tid; i < 4096; i += 1024) {
      int r = i >> 6, c4 = (i & 63) << 2;
      const float4 w = *reinterpret_cast<const float4*>(
          p.W_ih + (size_t)(n0c + r) * (Eq + Dq) + Eq + kc + c4);
      WsCtx[c4 + 0][r] = f2bf(w.x); WsCtx[c4 + 1][r] = f2bf(w.y);
      WsCtx[c4 + 2][r] = f2bf(w.z); WsCtx[c4 + 3][r] = f2bf(w.w);
    }
    const int fb = blk >> 2, fp0 = (blk & 3) * 49;
    const ushort* src = p.fproj16 + ((size_t)fb * Pq + fp0) * Eq;
    for (int i = tid; i < 49 * 512 / 8; i += 1024) {
      reinterpret_cast<uint4*>(Fs)[i] = reinterpret_cast<const uint4*>(src)[i];
    }
    __syncthreads();
  }

  const int tx = tid & 15, ty = tid >> 4;
  const int n0c = (blk & 31) * 64, ksc = blk >> 5;

  for (int t = 0; t < Tq; ++t) {
    const float* hc = (t == 0) ? p.h0 : p.hseq + (size_t)(t - 1) * Bq * Eq;

    // ---- PA ----
    if (blk < 208) {
      float acc[4] = {};
      float* Pout; int n0, Npad;
      if (blk < 16) {
        int ks = blk >> 3; n0 = (blk & 7) * 64; Npad = Eq;
        gemm_ldsw<0>(hc, Eq, ks * 256, WsRole, nullptr, nullptr, t, As, tid, acc);
        Pout = p.Pah + (size_t)ks * Bq * Eq;
      } else if (blk < 80) {
        int i2 = blk - 16, ks = i2 >> 5; n0 = (i2 & 31) * 64; Npad = Dq;
        gemm_ldsw<0>(hc, Eq, ks * 256, WsRole, nullptr, nullptr, t, As, tid, acc);
        Pout = p.Pfb + (size_t)ks * Bq * Dq;
      } else if (blk < 144) {
        int i2 = blk - 80, ks = i2 >> 5; n0 = (i2 & 31) * 64; Npad = Dq;
        gemm_ldsw<0>(hc, Eq, ks * 256, WsRole, nullptr, nullptr, t, As, tid, acc);
        Pout = p.Pwh + (size_t)ks * Bq * Dq;
      } else {
        int i2 = blk - 144, ks = i2 >> 5; n0 = (i2 & 31) * 64; Npad = Dq;
        gemm_ldsw<1>(nullptr, 0, ks * 256, WsRole, p.emb, p.caps, t, As, tid, acc);
        Pout = p.Pge + (size_t)ks * Bq * Dq;
      }
      float* dst = Pout + (size_t)ty * Npad + n0 + tx * 4;
      coh_store2(dst, acc[0], acc[1]);
      coh_store2(dst + 2, acc[2], acc[3]);
    }
    gsync(p.bar);

    // ---- PB1: e-scores from LDS fproj slice ----
    {
      const int b = blk >> 2, pq = blk & 3;
      const int lane = tid & 63, wv = tid >> 6;
      float* ah = scr; float* vs = scr + 512;
      if (tid < Eq) {
        ah[tid] = p.b_Uatt[tid] + coh_load(&p.Pah[(size_t)b * Eq + tid])
                + coh_load(&p.Pah[(size_t)Bq * Eq + b * Eq + tid]);
        vs[tid] = p.v_att[tid];
      }
      __syncthreads();
      const float bv = p.b_vatt[0];
      const int pbeg = pq * 49;
      const int k8 = lane * 8;
      for (int pl = wv; pl < 49; pl += 16) {
        const ushort* f0 = Fs + pl * Eq + k8;
        uint4 va = *reinterpret_cast<const uint4*>(f0);
        float s = 0.f;
        const unsigned u[4] = {va.x, va.y, va.z, va.w};
#pragma unroll
        for (int j = 0; j < 4; ++j) {
          s = fmaf(tanhf(bf2f((ushort)(u[j] & 0xffffu)) + ah[k8 + j * 2]), vs[k8 + j * 2], s);
          s = fmaf(tanhf(bf2f((ushort)(u[j] >> 16)) + ah[k8 + j * 2 + 1]), vs[k8 + j * 2 + 1], s);
        }
#pragma unroll
        for (int off = 32; off > 0; off >>= 1) s += __shfl_xor(s, off);
        if (lane == 0) coh_store(&p.ev_g[b * 256 + pbeg + pl], s + bv);
      }
      __syncthreads();
    }
    gsync(p.bar);

    // ---- PB2: softmax (redundant x4) + gated context from PERMUTED img16p ----
    {
      const int b = blk >> 2, sl = blk & 3;
      float* pc = scr;            // 4096
      float* al = scr + 4096;     // 196
      float* red = scr + 4352;    // 256
      float x = (tid < Pq) ? coh_load(&p.ev_g[b * 256 + tid]) : -INFINITY;
      if (tid < 256) red[tid] = x;
      __syncthreads();
      for (int s2 = 128; s2 > 0; s2 >>= 1) {
        if (tid < s2) red[tid] = fmaxf(red[tid], red[tid + s2]);
        __syncthreads();
      }
      float mx = red[0];
      __syncthreads();
      float ex = (tid < Pq) ? expf(x - mx) : 0.f;
      if (tid < 256) red[tid] = ex;
      __syncthreads();
      for (int s2 = 128; s2 > 0; s2 >>= 1) {
        if (tid < s2) red[tid] += red[tid + s2];
        __syncthreads();
      }
      float inv = 1.f / red[0];
      if (tid < Pq) {
        float a = ex * inv;
        al[tid] = a;
        if (sl == 0) p.alphas_out[((size_t)b * Tq + t) * Pq + tid] = a;
      }
      __syncthreads();
      // context: block's 200KB is fully sequential in img16p
      const int tid2 = tid & 127, ph = tid >> 7;
      const int d4 = tid2 * 4;
      const int pb2 = (ph * 196) >> 3, pe2 = ((ph + 1) * 196) >> 3;
      const ushort* ib = p.img16p + ((size_t)(b * 4 + sl) * Pq) * 512 + d4;
      float s0 = 0.f, s1 = 0.f, s2a = 0.f, s3 = 0.f;
      for (int pp = pb2; pp < pe2; ++pp) {
        uint2 v = *reinterpret_cast<const uint2*>(ib + (size_t)pp * 512);
        float a = al[pp];
        s0 = fmaf(a, bf2f((ushort)(v.x & 0xffffu)), s0);
        s1 = fmaf(a, bf2f((ushort)(v.x >> 16)), s1);
        s2a = fmaf(a, bf2f((ushort)(v.y & 0xffffu)), s2a);
        s3 = fmaf(a, bf2f((ushort)(v.y >> 16)), s3);
      }
      *reinterpret_cast<float4*>(&pc[ph * 512 + d4]) = make_float4(s0, s1, s2a, s3);
      __syncthreads();
      if (tid < 512) {
        float sum = 0.f;
#pragma unroll
        for (int q = 0; q < 8; ++q) sum += pc[q * 512 + tid];
        int dd = sl * 512 + tid;
        float g = sigf(p.b_fbeta[dd] + coh_load(&p.Pfb[(size_t)b * Dq + dd])
                       + coh_load(&p.Pfb[(size_t)Bq * Dq + b * Dq + dd]));
        coh_store(&p.ctxg[(size_t)b * Dq + dd], sum * g);
      }
      __syncthreads();
    }
    gsync(p.bar);

    // ---- PC ----
    {
      float acc[4] = {};
      gemm_ldsw<0>(p.ctxg, Dq, ksc * 256, WsCtx, nullptr, nullptr, t, As, tid, acc);
      float* dst = p.Pg + (size_t)ksc * Bq * Dq + (size_t)ty * Dq + n0c + tx * 4;
      coh_store2(dst, acc[0], acc[1]);
      coh_store2(dst + 2, acc[2], acc[3]);
    }
    gsync(p.bar);

    // ---- PD ----
    if (blk < 32) {
      int idx = blk * 1024 + tid;
      int b = idx >> 9, e = idx & 511;
      float g0 = p.b_ih[e] + p.b_hh[e];
      float g1 = p.b_ih[Eq + e] + p.b_hh[Eq + e];
      float g2 = p.b_ih[2 * Eq + e] + p.b_hh[2 * Eq + e];
      float g3 = p.b_ih[3 * Eq + e] + p.b_hh[3 * Eq + e];
#pragma unroll
      for (int s = 0; s < 2; ++s) {
        const float* Pr = p.Pwh + ((size_t)s * Bq + b) * Dq;
        g0 += coh_load(Pr + e); g1 += coh_load(Pr + Eq + e);
        g2 += coh_load(Pr + 2 * Eq + e); g3 += coh_load(Pr + 3 * Eq + e);
      }
#pragma unroll
      for (int s = 0; s < 2; ++s) {
        const float* Pr = p.Pge + ((size_t)s * Bq + b) * Dq;
        g0 += coh_load(Pr + e); g1 += coh_load(Pr + Eq + e);
        g2 += coh_load(Pr + 2 * Eq + e); g3 += coh_load(Pr + 3 * Eq + e);
      }
#pragma unroll
      for (int s = 0; s < 8; ++s) {
        const float* Pr = p.Pg + ((size_t)s * Bq + b) * Dq;
        g0 += coh_load(Pr + e); g1 += coh_load(Pr + Eq + e);
        g2 += coh_load(Pr + 2 * Eq + e); g3 += coh_load(Pr + 3 * Eq + e);
      }
      float ig = sigf(g0), fg = sigf(g1), gg = tanhf(g2), og = sigf(g3);
      float cn = fg * p.c[idx] + ig * gg;
      p.c[idx] = cn;
      coh_store(&p.hseq[(size_t)t * Bq * Eq + idx], og * tanhf(cn));
    }
    gsync(p.bar);
  }
}

// ---------------- final batched preds GEMM (fp32, BM=128 BN=64) ----------------
__global__ __launch_bounds__(256) void gemm_out_big(const float* __restrict__ hseq,
                                                    const float* __restrict__ W_out,
                                                    const float* __restrict__ b_out,
                                                    float* __restrict__ out) {
  __shared__ float As[32][132];
  __shared__ float Ws[32][68];
  const int tid = threadIdx.x;
  const int tx = tid & 15, ty = tid >> 4;
  const int m0 = blockIdx.x * 128, n0 = blockIdx.y * 64;
  float acc[8][4] = {};
  for (int k0 = 0; k0 < Eq; k0 += 32) {
#pragma unroll
    for (int i = 0; i < 4; ++i) {
      int idx = tid + i * 256;
      int r = idx >> 3, c = (idx & 7) << 2;
      const float4 a = *reinterpret_cast<const float4*>(hseq + (size_t)(m0 + r) * Eq + k0 + c);
      As[c + 0][r] = a.x; As[c + 1][r] = a.y; As[c + 2][r] = a.z; As[c + 3][r] = a.w;
    }
#pragma unroll
    for (int i = 0; i < 2; ++i) {
      int idx = tid + i * 256;
      int r = idx >> 3, c = (idx & 7) << 2;
      int wr2 = n0 + r; if (wr2 >= Vq) wr2 = Vq - 1;
      const float4 w = *reinterpret_cast<const float4*>(W_out + (size_t)wr2 * Eq + k0 + c);
      Ws[c + 0][r] = w.x; Ws[c + 1][r] = w.y; Ws[c + 2][r] = w.z; Ws[c + 3][r] = w.w;
    }
    __syncthreads();
#pragma unroll
    for (int k = 0; k < 32; ++k) {
      float a[8], w[4];
#pragma unroll
      for (int i = 0; i < 8; ++i) a[i] = As[k][ty * 8 + i];
#pragma unroll
      for (int j = 0; j < 4; ++j) w[j] = Ws[k][tx * 4 + j];
#pragma unroll
      for (int i = 0; i < 8; ++i)
#pragma unroll
        for (int j = 0; j < 4; ++j) acc[i][j] = fmaf(a[i], w[j], acc[i][j]);
    }
    __syncthreads();
  }
#pragma unroll
  for (int j = 0; j < 4; ++j) {
    int n = n0 + tx * 4 + j;
    if (n < Vq) {
      float bv = b_out[n];
#pragma unroll
      for (int i = 0; i < 8; ++i) {
        int m = m0 + ty * 8 + i;
        int t = m >> 6, b = m & 63;
        out[((size_t)b * Tq + t) * Vq + n] = acc[i][j] + bv;
      }
    }
  }
}

}  // namespace

extern "C" void kernel_launch(void* const* d_in, const int* in_sizes, int n_in,
                              void* d_out, int out_size, void* d_ws, size_t ws_size,
                              hipStream_t stream) {
  (void)in_sizes; (void)n_in; (void)out_size; (void)ws_size;
  const float* img      = (const float*)d_in[0];
  const int*   caps     = (const int*)d_in[1];
  const float* emb      = (const float*)d_in[2];
  const float* W_init_h = (const float*)d_in[3];
  const float* b_init_h = (const float*)d_in[4];
  const float* W_init_c = (const float*)d_in[5];
  const float* b_init_c = (const float*)d_in[6];
  const float* W_fbeta  = (const float*)d_in[7];
  const float* b_fbeta  = (const float*)d_in[8];
  const float* U_att    = (const float*)d_in[9];
  const float* b_Uatt   = (const float*)d_in[10];
  const float* W_att    = (const float*)d_in[11];
  const float* b_Watt   = (const float*)d_in[12];
  const float* v_att    = (const float*)d_in[13];
  const float* b_vatt   = (const float*)d_in[14];
  const float* W_ih     = (const float*)d_in[15];
  const float* b_ih     = (const float*)d_in[16];
  const float* W_hh     = (const float*)d_in[17];
  const float* b_hh     = (const float*)d_in[18];
  const float* W_out    = (const float*)d_in[19];
  const float* b_out    = (const float*)d_in[20];

  float* out = (float*)d_out;
  float* alphas_out = out + (size_t)Bq * Tq * Vq;

  float* ws = (float*)d_ws;
  ushort* img16p  = (ushort*)ws; ws += N_IMG / 2;
  ushort* Watt16  = (ushort*)ws; ws += ((size_t)Eq * Dq) / 2;
  ushort* fproj16 = (ushort*)ws; ws += ((size_t)Bq * Pq * Eq) / 2;
  float* hseq  = ws; ws += (size_t)Tq * Bq * Eq;
  float* h0    = ws; ws += Bq * Eq;
  float* c     = ws; ws += Bq * Eq;
  float* ctxg  = ws; ws += Bq * Dq;
  float* ev_g  = ws; ws += Bq * 256;
  float* Pah   = ws; ws += (size_t)2 * Bq * Eq;
  float* Pfb   = ws; ws += (size_t)2 * Bq * Dq;
  float* Pwh   = ws; ws += (size_t)2 * Bq * Dq;
  float* Pge   = ws; ws += (size_t)2 * Bq * Dq;
  float* Pg    = ws; ws += (size_t)8 * Bq * Dq;
  float* avg   = ws; ws += Bq * Dq;
  float* initP = ws; ws += (size_t)16 * Bq * Eq;
  unsigned* bar = (unsigned*)ws; ws += 256;

  // ---- prolog ----
  bar_init<<<1, 256, 0, stream>>>(bar);
  cvt_all<<<(int)((N_IMG / 8 + (size_t)Eq * Dq / 8) / 256), 256, 0, stream>>>(img, W_att, img16p,
                                                                              Watt16);
  avg_kernel<<<Bq * Dq / 256, 256, 0, stream>>>(img, avg);
  init_partial<<<dim3(8, 8, 2), 256, 0, stream>>>(avg, W_init_h, W_init_c, initP);
  init_epi<<<2 * Bq * Eq / 256, 256, 0, stream>>>(initP, b_init_h, b_init_c, h0, c);
  fproj_mfma<<<dim3(Bq * Pq / 128, Eq / 64), 256, 0, stream>>>(img16p, Watt16, b_Watt, fproj16);

  // ---- 32-step recurrence ----
  StepParams sp;
  sp.caps = caps; sp.emb = emb; sp.U_att = U_att; sp.b_Uatt = b_Uatt;
  sp.W_fbeta = W_fbeta; sp.b_fbeta = b_fbeta; sp.v_att = v_att; sp.b_vatt = b_vatt;
  sp.W_ih = W_ih; sp.b_ih = b_ih; sp.W_hh = W_hh; sp.b_hh = b_hh;
  sp.img16p = img16p; sp.fproj16 = fproj16; sp.h0 = h0;
  sp.c = c; sp.hseq = hseq; sp.ctxg = ctxg; sp.ev_g = ev_g;
  sp.Pah = Pah; sp.Pfb = Pfb; sp.Pwh = Pwh; sp.Pge = Pge; sp.Pg = Pg;
  sp.alphas_out = alphas_out; sp.bar = bar;
  step_loop<<<NBLK, 1024, 0, stream>>>(sp);

  // ---- batched preds GEMM ----
  gemm_out_big<<<dim3(Tq * Bq / 128, 157), 256, 0, stream>>>(hseq, W_out, b_out, out);
}